// Round 9
// baseline (551.450 us; speedup 1.0000x reference)
//
#include <hip/hip_runtime.h>
#include <hip/hip_bf16.h>
#include <stdint.h>

typedef unsigned short u16;
typedef __attribute__((ext_vector_type(8))) short short8;
typedef __attribute__((ext_vector_type(4))) float f32x4;
typedef __attribute__((ext_vector_type(4))) int i32x4;
typedef __attribute__((ext_vector_type(2))) unsigned int u32x2;

#define B_    2
#define S_    2048
#define D_    1024
#define H_    16
#define T_    (B_*S_)

static __device__ __forceinline__ float b2f(u16 h) { return __uint_as_float(((uint32_t)h) << 16); }
static __device__ __forceinline__ u16 f2b(float f) {
    uint32_t u = __float_as_uint(f);
    u += 0x7fffu + ((u >> 16) & 1u);          // RNE
    return (u16)(u >> 16);
}
static __device__ __forceinline__ uint32_t pack2(float a, float b) {
    return (uint32_t)f2b(a) | ((uint32_t)f2b(b) << 16);
}
static __device__ __forceinline__ uint32_t cvtpk(float a, float b) {
    uint32_t r;
    asm("v_cvt_pk_bf16_f32 %0, %1, %2" : "=v"(r) : "v"(a), "v"(b));
    return r;
}
#define MFMA(a,b,c) __builtin_amdgcn_mfma_f32_16x16x32_bf16(a,b,c,0,0,0)

// async global->LDS, 16B per lane; lds dest = wave-uniform base + lane*16B
static __device__ __forceinline__ void gl2lds16(const void* g, void* l) {
    __builtin_amdgcn_global_load_lds((const __attribute__((address_space(1))) void*)g,
                                     (__attribute__((address_space(3))) void*)l, 16, 0, 0);
}

// ---------------- transpose cores ----------------
static __device__ __forceinline__ void tr_body(const float* __restrict__ ip,
    u16* __restrict__ op, int K, int N, int k0, int n0, float (*tile)[33])
{
    int tx = threadIdx.x, ty = threadIdx.y;   // 32 x 8
#pragma unroll
    for (int i = 0; i < 4; ++i) {
        int k = k0 + ty + 8 * i, n = n0 + tx;
        tile[ty + 8 * i][tx] = (k < K && n < N) ? ip[(long)k * N + n] : 0.f;
    }
    __syncthreads();
#pragma unroll
    for (int i = 0; i < 4; ++i) {
        int n = n0 + ty + 8 * i, k = k0 + tx;
        if (n < N && k < K) op[(long)n * K + k] = f2b(tile[tx][ty + 8 * i]);
    }
}

// gate|up transpose with interleave-permuted destination rows:
// src col n (0..511), dest row = 128*(n>>6) + 64*((n>>5)&1) + (is_up?32:0) + (n&31)
// -> each 128-row block of wgu_t holds gate[64t..64t+63] and up[same cols],
//    paired within-lane in the GEMM epilogue (ni <-> ni+2).
static __device__ __forceinline__ void tr_body_perm(const float* __restrict__ ip,
    u16* __restrict__ op, int k0, int n0, int is_up, float (*tile)[33])
{
    int tx = threadIdx.x, ty = threadIdx.y;   // 32 x 8; K=1024, N=512
#pragma unroll
    for (int i = 0; i < 4; ++i) {
        int k = k0 + ty + 8 * i, n = n0 + tx;
        tile[ty + 8 * i][tx] = ip[(long)k * 512 + n];
    }
    __syncthreads();
#pragma unroll
    for (int i = 0; i < 4; ++i) {
        int n = n0 + ty + 8 * i, k = k0 + tx;
        int nr = 128 * (n >> 6) + 64 * ((n >> 5) & 1) + (is_up ? 32 : 0) + (n & 31);
        op[(long)nr * 1024 + k] = f2b(tile[tx][ty + 8 * i]);
    }
}

// attn weights group A: w_q | w_dkv | w_kr (all K=1024), grid (82, 32)
__global__ __launch_bounds__(256) void transpose_attn_a(const float* __restrict__ wq,
    const float* __restrict__ wdkv, const float* __restrict__ wkr, u16* __restrict__ out)
{
    __shared__ float tile[32][33];
    int bx = blockIdx.x;
    const float* in; u16* op; int N; int n0;
    if (bx < 64)      { in = wq;   op = out;             N = 2048; n0 = bx * 32; }
    else if (bx < 80) { in = wdkv; op = out + 2048*1024; N = 512;  n0 = (bx-64) * 32; }
    else              { in = wkr;  op = out + 2560*1024; N = 64;   n0 = (bx-80) * 32; }
    tr_body(in, op, 1024, N, blockIdx.y * 32, n0, tile);
}

// attn weights group B: w_uk | w_uv | w_o (N=1024), grid (32, 64)
__global__ __launch_bounds__(256) void transpose_attn_b(const float* __restrict__ wuk,
    const float* __restrict__ wuv, const float* __restrict__ wo,
    u16* __restrict__ uk_t, u16* __restrict__ uv_t, u16* __restrict__ wo_t)
{
    __shared__ float tile[32][33];
    int by = blockIdx.y;
    const float* in; u16* op; int K; int k0;
    if (by < 16)      { in = wuk; op = uk_t; K = 512;  k0 = by * 32; }
    else if (by < 32) { in = wuv; op = uv_t; K = 512;  k0 = (by-16) * 32; }
    else              { in = wo;  op = wo_t; K = 1024; k0 = (by-32) * 32; }
    tr_body(in, op, K, 1024, k0, blockIdx.x * 32, tile);
}

// ALL MoE weight transposes in one launch, grid (32, 32, 30)
// z<20: gate|up (permuted rows): z<8 r_gate, z<16 r_up, z<18 s_gate, z<20 s_up
// z>=20: down: z-20<8 routed, else shared
__global__ __launch_bounds__(256) void transpose_moe(const float* __restrict__ wr_gate,
    const float* __restrict__ wr_up, const float* __restrict__ ws_gate,
    const float* __restrict__ ws_up, const float* __restrict__ wr_down,
    const float* __restrict__ ws_down, u16* __restrict__ wgu_t, u16* __restrict__ wd_t)
{
    __shared__ float tile[32][33];
    int z = blockIdx.z;
    if (z < 20) {
        if (blockIdx.x >= 16) return;
        const float* in; u16* op; int is_up;
        if (z < 8)       { in = wr_gate + (long)z * 524288;      op = wgu_t + (long)z * 1048576;      is_up = 0; }
        else if (z < 16) { in = wr_up   + (long)(z-8) * 524288;  op = wgu_t + (long)(z-8) * 1048576;  is_up = 1; }
        else if (z < 18) { in = ws_gate + (long)(z-16) * 524288; op = wgu_t + (long)(z-8) * 1048576;  is_up = 0; }
        else             { in = ws_up   + (long)(z-18) * 524288; op = wgu_t + (long)(z-10) * 1048576; is_up = 1; }
        tr_body_perm(in, op, blockIdx.y * 32, blockIdx.x * 32, is_up, tile);
    } else {
        if (blockIdx.y >= 16) return;
        int zz = z - 20;
        const float* in = (zz < 8) ? wr_down + (long)zz * 524288 : ws_down + (long)(zz-8) * 524288;
        u16* op = wd_t + (long)zz * 524288;
        tr_body(in, op, 512, 1024, blockIdx.y * 32, blockIdx.x * 32, tile);
    }
}

// ---------------- MFMA GEMM, depth-2 pipelined; optional fused RoPE epilogue ----------------
// mode: 1 = bf16 store, 2 = f32 +=, 3 = f32 store of (v + resid)
// ropeflg (qkv only): rotation on f32 acc for q heads (tile<16, wn==64) and kr (tile 20, wn==0).
__global__ __launch_bounds__(256) void gemm_k(const u16* __restrict__ A, long lda,
    const u16* __restrict__ Bt, long ldb, void* __restrict__ Cv, long ldc, int K,
    int mode, const float* __restrict__ resid, int ropeflg)
{
    __shared__ u16 As[3][128 * 32];
    __shared__ u16 Bs[3][128 * 32];
    const int tid = threadIdx.x, lane = tid & 63, wave = tid >> 6;
    const int wm = (wave & 1) * 64, wn = (wave >> 1) * 64;
    const int quad = lane >> 4, rr = lane & 15, q8 = quad * 8;
    const long row0 = (long)blockIdx.y * 128, col0 = (long)blockIdx.x * 128;
    f32x4 acc[4][4];
#pragma unroll
    for (int i = 0; i < 4; ++i)
#pragma unroll
        for (int j = 0; j < 4; ++j)
#pragma unroll
            for (int c = 0; c < 4; ++c) acc[i][j][c] = 0.f;
    const int band = wave * 32;
    const u16* ga = A + (row0 + band + (lane >> 2)) * lda + (lane & 3) * 8;
    const u16* gb = Bt + (col0 + band + (lane >> 2)) * ldb + (lane & 3) * 8;
    const int lo = band * 32;
    const int nt = K >> 5;
#define STG(bi, k0s) do { \
    gl2lds16(ga + (k0s), &As[bi][lo]); \
    gl2lds16(ga + (k0s) + 16 * lda, &As[bi][lo + 512]); \
    gl2lds16(gb + (k0s), &Bs[bi][lo]); \
    gl2lds16(gb + (k0s) + 16 * ldb, &Bs[bi][lo + 512]); } while (0)
    STG(0, 0);
    STG(1, 32);
    asm volatile("s_waitcnt vmcnt(4)" ::: "memory");
    __builtin_amdgcn_s_barrier();
    int cur = 0, nx2 = 2;
    for (int t = 0; t < nt; ++t) {
        const bool more = (t + 2 < nt);
        if (more) STG(nx2, (t + 2) * 32);
        short8 af[4], bf[4];
#pragma unroll
        for (int mi = 0; mi < 4; ++mi) af[mi] = *(const short8*)&As[cur][(wm + mi * 16 + rr) * 32 + q8];
#pragma unroll
        for (int ni = 0; ni < 4; ++ni) bf[ni] = *(const short8*)&Bs[cur][(wn + ni * 16 + rr) * 32 + q8];
#pragma unroll
        for (int mi = 0; mi < 4; ++mi)
#pragma unroll
            for (int ni = 0; ni < 4; ++ni)
                acc[mi][ni] = MFMA(af[mi], bf[ni], acc[mi][ni]);
        if (more) asm volatile("s_waitcnt vmcnt(4)" ::: "memory");
        else      asm volatile("s_waitcnt vmcnt(0)" ::: "memory");
        __builtin_amdgcn_s_barrier();
        cur = (cur == 2) ? 0 : cur + 1;
        nx2 = (nx2 == 2) ? 0 : nx2 + 1;
    }
#undef STG
    // fused RoPE: pairs (i, i+32) are acc[mi][ni] <-> acc[mi][ni+2] within this lane
    if (ropeflg && (((int)blockIdx.x < 16 && wn == 64) || ((int)blockIdx.x == 20 && wn == 0))) {
#pragma unroll
        for (int ni = 0; ni < 2; ++ni) {
            const int i = ni * 16 + rr;
            const float inv = __expf(-(float)i * 0.28782313662425575f);  // ln(10000)/32
#pragma unroll
            for (int mi = 0; mi < 4; ++mi)
#pragma unroll
                for (int rg = 0; rg < 4; ++rg) {
                    int srow = (int)((row0 + wm + mi * 16 + quad * 4 + rg) & (S_ - 1));
                    float ang = (float)srow * inv;
                    float cc = cosf(ang), ss = sinf(ang);
                    float t1 = acc[mi][ni][rg], t2 = acc[mi][ni + 2][rg];
                    acc[mi][ni][rg]     = t1 * cc - t2 * ss;
                    acc[mi][ni + 2][rg] = t2 * cc + t1 * ss;
                }
        }
    }
#pragma unroll
    for (int mi = 0; mi < 4; ++mi)
#pragma unroll
        for (int ni = 0; ni < 4; ++ni)
#pragma unroll
            for (int rg = 0; rg < 4; ++rg) {
                long r = row0 + wm + mi * 16 + quad * 4 + rg;
                long c = col0 + wn + ni * 16 + rr;
                float v = acc[mi][ni][rg];
                if (mode == 1)      ((u16*)Cv)[r * ldc + c] = f2b(v);
                else if (mode == 2) ((float*)Cv)[r * ldc + c] += v;
                else                ((float*)Cv)[r * ldc + c] = v + resid[r * 1024 + c];
            }
}

// ---------------- dual independent GEMM (both K=512, bf16 store), z picks desc ----------------
__global__ __launch_bounds__(256) void gemm_dual(
    const u16* __restrict__ A0, long lda0, const u16* __restrict__ B0, long ldb0, u16* __restrict__ C0, long ldc0, int nx0, int ny0,
    const u16* __restrict__ A1, long lda1, const u16* __restrict__ B1, long ldb1, u16* __restrict__ C1, long ldc1, int nx1, int ny1)
{
    const int z = blockIdx.z;
    if ((int)blockIdx.x >= (z ? nx1 : nx0) || (int)blockIdx.y >= (z ? ny1 : ny0)) return;
    const u16* A  = z ? A1 : A0;  const long lda = z ? lda1 : lda0;
    const u16* Bt = z ? B1 : B0;  const long ldb = z ? ldb1 : ldb0;
    u16* C = z ? C1 : C0;         const long ldc = z ? ldc1 : ldc0;
    __shared__ u16 As[3][128 * 32];
    __shared__ u16 Bs[3][128 * 32];
    const int tid = threadIdx.x, lane = tid & 63, wave = tid >> 6;
    const int wm = (wave & 1) * 64, wn = (wave >> 1) * 64;
    const int quad = lane >> 4, rr = lane & 15, q8 = quad * 8;
    const long row0 = (long)blockIdx.y * 128, col0 = (long)blockIdx.x * 128;
    f32x4 acc[4][4];
#pragma unroll
    for (int i = 0; i < 4; ++i)
#pragma unroll
        for (int j = 0; j < 4; ++j)
#pragma unroll
            for (int c = 0; c < 4; ++c) acc[i][j][c] = 0.f;
    const int band = wave * 32;
    const u16* ga = A + (row0 + band + (lane >> 2)) * lda + (lane & 3) * 8;
    const u16* gb = Bt + (col0 + band + (lane >> 2)) * ldb + (lane & 3) * 8;
    const int lo = band * 32;
    const int nt = 16;   // K=512
#define STG(bi, k0s) do { \
    gl2lds16(ga + (k0s), &As[bi][lo]); \
    gl2lds16(ga + (k0s) + 16 * lda, &As[bi][lo + 512]); \
    gl2lds16(gb + (k0s), &Bs[bi][lo]); \
    gl2lds16(gb + (k0s) + 16 * ldb, &Bs[bi][lo + 512]); } while (0)
    STG(0, 0);
    STG(1, 32);
    asm volatile("s_waitcnt vmcnt(4)" ::: "memory");
    __builtin_amdgcn_s_barrier();
    int cur = 0, nx2 = 2;
    for (int t = 0; t < nt; ++t) {
        const bool more = (t + 2 < nt);
        if (more) STG(nx2, (t + 2) * 32);
        short8 af[4], bf[4];
#pragma unroll
        for (int mi = 0; mi < 4; ++mi) af[mi] = *(const short8*)&As[cur][(wm + mi * 16 + rr) * 32 + q8];
#pragma unroll
        for (int ni = 0; ni < 4; ++ni) bf[ni] = *(const short8*)&Bs[cur][(wn + ni * 16 + rr) * 32 + q8];
#pragma unroll
        for (int mi = 0; mi < 4; ++mi)
#pragma unroll
            for (int ni = 0; ni < 4; ++ni)
                acc[mi][ni] = MFMA(af[mi], bf[ni], acc[mi][ni]);
        if (more) asm volatile("s_waitcnt vmcnt(4)" ::: "memory");
        else      asm volatile("s_waitcnt vmcnt(0)" ::: "memory");
        __builtin_amdgcn_s_barrier();
        cur = (cur == 2) ? 0 : cur + 1;
        nx2 = (nx2 == 2) ? 0 : nx2 + 1;
    }
#undef STG
#pragma unroll
    for (int mi = 0; mi < 4; ++mi)
#pragma unroll
        for (int ni = 0; ni < 4; ++ni)
#pragma unroll
            for (int rg = 0; rg < 4; ++rg) {
                long r = row0 + wm + mi * 16 + quad * 4 + rg;
                long c = col0 + wn + ni * 16 + rr;
                C[r * ldc + c] = f2b(acc[mi][ni][rg]);
            }
}

// ---------------- gate|up + FUSED SiLU for ALL experts ----------------
// z<8 routed (gathered), z=8,9 shared. B rows interleaved (gate j at row 128t+64h+j,
// up j at +32) so silu pairs are within-lane: g=acc[mi][ni], u=acc[mi][ni+2], ni<2.
// Output: act_r[slot][512] (routed), act_s[token][1024] (shared: e8 cols 0-511, e9 512-1023).
__global__ __launch_bounds__(256) void gemm_guall(const u16* __restrict__ H2,
    const u16* __restrict__ BtAll, u16* __restrict__ act_r, u16* __restrict__ act_s,
    const int* __restrict__ cnt, const int* __restrict__ off, const int* __restrict__ elist)
{
    const int e = blockIdx.z;
    const bool sh = (e >= 8);
    const int cntE = sh ? 4096 : cnt[e];
    const int offE = sh ? 0 : off[e];
    const int m0 = blockIdx.y * 128;
    if (m0 >= cntE) return;
    const u16* Bt = BtAll + (long)e * 1048576;
    __shared__ u16 As[3][128 * 32];
    __shared__ u16 Bs[3][128 * 32];
    const int tid = threadIdx.x, lane = tid & 63, wave = tid >> 6;
    const int wm = (wave & 1) * 64, wn = (wave >> 1) * 64;
    const int quad = lane >> 4, rr = lane & 15, q8 = quad * 8;
    f32x4 acc[4][4];
#pragma unroll
    for (int i = 0; i < 4; ++i)
#pragma unroll
        for (int j = 0; j < 4; ++j)
#pragma unroll
            for (int c = 0; c < 4; ++c) acc[i][j][c] = 0.f;
    const int band = wave * 32;
    int r0 = m0 + band + (lane >> 2);
    int r1 = r0 + 16;
    int tok0, tok1;
    if (sh) { tok0 = r0; tok1 = r1; }
    else {
        tok0 = elist[offE + (r0 < cntE ? r0 : cntE - 1)];
        tok1 = elist[offE + (r1 < cntE ? r1 : cntE - 1)];
    }
    const u16* ga0 = H2 + (long)tok0 * 1024 + (lane & 3) * 8;
    const u16* ga1 = H2 + (long)tok1 * 1024 + (lane & 3) * 8;
    const u16* gb = Bt + ((long)blockIdx.x * 128 + band + (lane >> 2)) * 1024L + (lane & 3) * 8;
    const int lo = band * 32;
#define STG(bi, k0s) do { \
    gl2lds16(ga0 + (k0s), &As[bi][lo]); \
    gl2lds16(ga1 + (k0s), &As[bi][lo + 512]); \
    gl2lds16(gb + (k0s), &Bs[bi][lo]); \
    gl2lds16(gb + (k0s) + 16 * 1024, &Bs[bi][lo + 512]); } while (0)
    const int nt = 32;   // K=1024
    STG(0, 0);
    STG(1, 32);
    asm volatile("s_waitcnt vmcnt(4)" ::: "memory");
    __builtin_amdgcn_s_barrier();
    int cur = 0, nx2 = 2;
    for (int t = 0; t < nt; ++t) {
        const bool more = (t + 2 < nt);
        if (more) STG(nx2, (t + 2) * 32);
        short8 af[4], bf[4];
#pragma unroll
        for (int mi = 0; mi < 4; ++mi) af[mi] = *(const short8*)&As[cur][(wm + mi * 16 + rr) * 32 + q8];
#pragma unroll
        for (int ni = 0; ni < 4; ++ni) bf[ni] = *(const short8*)&Bs[cur][(wn + ni * 16 + rr) * 32 + q8];
#pragma unroll
        for (int mi = 0; mi < 4; ++mi)
#pragma unroll
            for (int ni = 0; ni < 4; ++ni)
                acc[mi][ni] = MFMA(af[mi], bf[ni], acc[mi][ni]);
        if (more) asm volatile("s_waitcnt vmcnt(4)" ::: "memory");
        else      asm volatile("s_waitcnt vmcnt(0)" ::: "memory");
        __builtin_amdgcn_s_barrier();
        cur = (cur == 2) ? 0 : cur + 1;
        nx2 = (nx2 == 2) ? 0 : nx2 + 1;
    }
#undef STG
    // fused silu(g)*u epilogue, within-lane pairing; writes 512-wide act
#pragma unroll
    for (int mi = 0; mi < 4; ++mi)
#pragma unroll
        for (int ni = 0; ni < 2; ++ni)
#pragma unroll
            for (int rg = 0; rg < 4; ++rg) {
                int ml = wm + mi * 16 + quad * 4 + rg;
                if (m0 + ml >= cntE) continue;
                int cout = 64 * (int)blockIdx.x + 32 * (wn >> 6) + ni * 16 + rr;
                float g = acc[mi][ni][rg], u = acc[mi][ni + 2][rg];
                float val = g / (1.f + __expf(-g)) * u;
                if (sh) act_s[(long)(m0 + ml) * 1024 + (long)(e - 8) * 512 + cout] = f2b(val);
                else    act_r[(long)(offE + m0 + ml) * 512 + cout] = f2b(val);
            }
}

// ---------------- down for ALL: z<8 routed (K=512 -> rout bf16), z=8 shared fused (K=1024 -> x_mid +=) ----------------
// grid (8, 32, 9); act_r 512-wide, act_s 1024-wide (aoff == k directly)
__global__ __launch_bounds__(256) void gemm_downall(const u16* __restrict__ act_r,
    const u16* __restrict__ act_s, const u16* __restrict__ WdAll, u16* __restrict__ rout,
    float* __restrict__ xmid, const int* __restrict__ cnt, const int* __restrict__ off)
{
    const int e = blockIdx.z;
    __shared__ u16 As[3][128 * 32];
    __shared__ u16 Bs[3][128 * 32];
    const int tid = threadIdx.x, lane = tid & 63, wave = tid >> 6;
    const int wm = (wave & 1) * 64, wn = (wave >> 1) * 64;
    const int quad = lane >> 4, rr = lane & 15, q8 = quad * 8;
    const long col0 = (long)blockIdx.x * 128;
    const int m0 = blockIdx.y * 128;
    const int band = wave * 32;
    const int lo = band * 32;
    f32x4 acc[4][4];
#pragma unroll
    for (int i = 0; i < 4; ++i)
#pragma unroll
        for (int j = 0; j < 4; ++j)
#pragma unroll
            for (int c = 0; c < 4; ++c) acc[i][j][c] = 0.f;
    if (e < 8) {
        const int cntE = cnt[e], offE = off[e];
        if (m0 >= cntE) return;
        const u16* Bt = WdAll + (long)e * 524288;
        int r0 = offE + m0 + band + (lane >> 2); if (r0 > 8191) r0 = 8191;
        int r1 = r0 + 16; if (r1 > 8191) r1 = 8191;
        const u16* ga0 = act_r + (long)r0 * 512 + (lane & 3) * 8;
        const u16* ga1 = act_r + (long)r1 * 512 + (lane & 3) * 8;
        const u16* gb = Bt + (col0 + band + (lane >> 2)) * 512L + (lane & 3) * 8;
#define STGR(bi, k0s) do { \
    gl2lds16(ga0 + (k0s), &As[bi][lo]); \
    gl2lds16(ga1 + (k0s), &As[bi][lo + 512]); \
    gl2lds16(gb + (k0s), &Bs[bi][lo]); \
    gl2lds16(gb + (k0s) + 16 * 512, &Bs[bi][lo + 512]); } while (0)
        const int nt = 16;   // K=512
        STGR(0, 0);
        STGR(1, 32);
        asm volatile("s_waitcnt vmcnt(4)" ::: "memory");
        __builtin_amdgcn_s_barrier();
        int cur = 0, nx2 = 2;
        for (int t = 0; t < nt; ++t) {
            const bool more = (t + 2 < nt);
            if (more) STGR(nx2, (t + 2) * 32);
            short8 af[4], bf[4];
#pragma unroll
            for (int mi = 0; mi < 4; ++mi) af[mi] = *(const short8*)&As[cur][(wm + mi * 16 + rr) * 32 + q8];
#pragma unroll
            for (int ni = 0; ni < 4; ++ni) bf[ni] = *(const short8*)&Bs[cur][(wn + ni * 16 + rr) * 32 + q8];
#pragma unroll
            for (int mi = 0; mi < 4; ++mi)
#pragma unroll
                for (int ni = 0; ni < 4; ++ni)
                    acc[mi][ni] = MFMA(af[mi], bf[ni], acc[mi][ni]);
            if (more) asm volatile("s_waitcnt vmcnt(4)" ::: "memory");
            else      asm volatile("s_waitcnt vmcnt(0)" ::: "memory");
            __builtin_amdgcn_s_barrier();
            cur = (cur == 2) ? 0 : cur + 1;
            nx2 = (nx2 == 2) ? 0 : nx2 + 1;
        }
#undef STGR
#pragma unroll
        for (int mi = 0; mi < 4; ++mi)
#pragma unroll
            for (int ni = 0; ni < 4; ++ni)
#pragma unroll
                for (int rg = 0; rg < 4; ++rg) {
                    int ml = wm + mi * 16 + quad * 4 + rg;
                    long c = col0 + wn + ni * 16 + rr;
                    if (m0 + ml < cntE)
                        rout[(long)(offE + m0 + ml) * 1024 + c] = f2b(acc[mi][ni][rg]);
                }
    } else {
        // shared fused down: x_mid += act8*wd8^T + act9*wd9^T (A = act_s 1024-wide)
        const u16* BtBase = WdAll + 8L * 524288;
        const long arow = m0 + band + (lane >> 2);
        const long brow = col0 + band + (lane >> 2);
#define STGS(bi, k0s) do { \
    const long boff = ((k0s) < 512) ? (long)(k0s) : (long)(524288 - 512 + (k0s)); \
    const u16* ga = act_s + arow * 1024 + (k0s) + (lane & 3) * 8; \
    const u16* gb = BtBase + brow * 512 + boff + (lane & 3) * 8; \
    gl2lds16(ga, &As[bi][lo]); \
    gl2lds16(ga + 16 * 1024, &As[bi][lo + 512]); \
    gl2lds16(gb, &Bs[bi][lo]); \
    gl2lds16(gb + 16 * 512, &Bs[bi][lo + 512]); } while (0)
        const int nt = 32;   // K=1024 equivalent
        STGS(0, 0);
        STGS(1, 32);
        asm volatile("s_waitcnt vmcnt(4)" ::: "memory");
        __builtin_amdgcn_s_barrier();
        int cur = 0, nx2 = 2;
        for (int t = 0; t < nt; ++t) {
            const bool more = (t + 2 < nt);
            if (more) STGS(nx2, (t + 2) * 32);
            short8 af[4], bf[4];
#pragma unroll
            for (int mi = 0; mi < 4; ++mi) af[mi] = *(const short8*)&As[cur][(wm + mi * 16 + rr) * 32 + q8];
#pragma unroll
            for (int ni = 0; ni < 4; ++ni) bf[ni] = *(const short8*)&Bs[cur][(wn + ni * 16 + rr) * 32 + q8];
#pragma unroll
            for (int mi = 0; mi < 4; ++mi)
#pragma unroll
                for (int ni = 0; ni < 4; ++ni)
                    acc[mi][ni] = MFMA(af[mi], bf[ni], acc[mi][ni]);
            if (more) asm volatile("s_waitcnt vmcnt(4)" ::: "memory");
            else      asm volatile("s_waitcnt vmcnt(0)" ::: "memory");
            __builtin_amdgcn_s_barrier();
            cur = (cur == 2) ? 0 : cur + 1;
            nx2 = (nx2 == 2) ? 0 : nx2 + 1;
        }
#undef STGS
#pragma unroll
        for (int mi = 0; mi < 4; ++mi)
#pragma unroll
            for (int ni = 0; ni < 4; ++ni)
#pragma unroll
                for (int rg = 0; rg < 4; ++rg) {
                    long r = m0 + wm + mi * 16 + quad * 4 + rg;
                    long c = col0 + wn + ni * 16 + rr;
                    xmid[r * 1024 + c] += acc[mi][ni][rg];
                }
    }
}

// ---------------- wave-per-token rmsnorm f32 -> bf16 (no barriers) ----------------
__global__ __launch_bounds__(256) void rmsnorm_wave(const float* __restrict__ x,
    const float* __restrict__ w, u16* __restrict__ out)
{
    const int t = blockIdx.x * 4 + (threadIdx.x >> 6);
    const int lane = threadIdx.x & 63;
    const float* xp = x + (size_t)t * D_;
    f32x4 v[4];
    float s = 0.f;
#pragma unroll
    for (int i = 0; i < 4; ++i) {
        v[i] = *(const f32x4*)&xp[lane * 4 + i * 256];
#pragma unroll
        for (int j = 0; j < 4; ++j) s += v[i][j] * v[i][j];
    }
#pragma unroll
    for (int o = 32; o > 0; o >>= 1) s += __shfl_xor(s, o);
    const float inv = rsqrtf(s * (1.f / D_) + 1e-6f);
    u16* op = out + (size_t)t * D_;
#pragma unroll
    for (int i = 0; i < 4; ++i) {
        const int d = lane * 4 + i * 256;
        f32x4 wv = *(const f32x4*)&w[d];
        u32x2 pk;
        pk[0] = pack2(v[i][0] * inv * wv[0], v[i][1] * inv * wv[1]);
        pk[1] = pack2(v[i][2] * inv * wv[2], v[i][3] * inv * wv[3]);
        *(u32x2*)&op[d] = pk;
    }
}

// ---------------- fused mlp-rmsnorm + gate: h2 + top2, wave-per-token, NO atomics ----------------
__global__ __launch_bounds__(256) void rmsnorm_gate_fused(const float* __restrict__ xm,
    const float* __restrict__ nw, const float* __restrict__ gw, u16* __restrict__ h2,
    int* __restrict__ tok_e, float* __restrict__ tok_w)
{
    const int t = blockIdx.x * 4 + (threadIdx.x >> 6);
    const int lane = threadIdx.x & 63;
    const float* xp = xm + (size_t)t * D_;
    f32x4 v[4];
    float s = 0.f;
#pragma unroll
    for (int i = 0; i < 4; ++i) {
        v[i] = *(const f32x4*)&xp[lane * 4 + i * 256];
#pragma unroll
        for (int j = 0; j < 4; ++j) s += v[i][j] * v[i][j];
    }
#pragma unroll
    for (int o = 32; o > 0; o >>= 1) s += __shfl_xor(s, o);
    const float inv = rsqrtf(s * (1.f / D_) + 1e-6f);
    u16* op = h2 + (size_t)t * D_;
    float part[8] = {0,0,0,0,0,0,0,0};
#pragma unroll
    for (int i = 0; i < 4; ++i) {
        const int d = lane * 4 + i * 256;
        f32x4 wv = *(const f32x4*)&nw[d];
        float hv[4];
#pragma unroll
        for (int j = 0; j < 4; ++j) hv[j] = v[i][j] * inv * wv[j];
        u32x2 pk;
        pk[0] = pack2(hv[0], hv[1]);
        pk[1] = pack2(hv[2], hv[3]);
        *(u32x2*)&op[d] = pk;
#pragma unroll
        for (int j = 0; j < 4; ++j) {
            const float* gp = gw + (size_t)(d + j) * 8;
#pragma unroll
            for (int e = 0; e < 8; ++e) part[e] += hv[j] * gp[e];
        }
    }
#pragma unroll
    for (int e = 0; e < 8; ++e)
#pragma unroll
        for (int o = 32; o > 0; o >>= 1) part[e] += __shfl_xor(part[e], o);
    if (lane == 0) {
        float mx = part[0];
#pragma unroll
        for (int e = 1; e < 8; ++e) mx = fmaxf(mx, part[e]);
        float p[8];
#pragma unroll
        for (int e = 0; e < 8; ++e) p[e] = __expf(part[e] - mx);
        int i0 = 0;
#pragma unroll
        for (int e = 1; e < 8; ++e) if (p[e] > p[i0]) i0 = e;
        int i1 = (i0 == 0) ? 1 : 0;
#pragma unroll
        for (int e = 0; e < 8; ++e) { if (e == i0) continue; if (p[e] > p[i1]) i1 = e; }
        float sw = p[i0] + p[i1];
        tok_e[2 * t] = i0;  tok_e[2 * t + 1] = i1;
        tok_w[2 * t] = p[i0] / sw;  tok_w[2 * t + 1] = p[i1] / sw;
    }
}

// ---------------- atomic-free routing: histogram + prefix + deterministic scatter ----------------
__global__ __launch_bounds__(256) void moe_route(const int* __restrict__ tok_e,
    int* __restrict__ cnt, int* __restrict__ off,
    int* __restrict__ elist, int* __restrict__ tslot)
{
    const int E = blockIdx.x;                 // expert this block owns
    const int tid = threadIdx.x, lane = tid & 63, wave = tid >> 6;
    int ev[32];
#pragma unroll
    for (int i = 0; i < 8; ++i)
        *(i32x4*)&ev[i * 4] = *(const i32x4*)&tok_e[tid * 32 + i * 4];
    int c8[8] = {0,0,0,0,0,0,0,0};
#pragma unroll
    for (int k = 0; k < 32; ++k) ++c8[ev[k] & 7];
    int incl[8];
#pragma unroll
    for (int e = 0; e < 8; ++e) {
        int vv = c8[e];
#pragma unroll
        for (int d = 1; d < 64; d <<= 1) {
            int tmp = __shfl_up(vv, d);
            if (lane >= d) vv += tmp;
        }
        incl[e] = vv;
    }
    __shared__ int wtot[4][8];
    if (lane == 63)
#pragma unroll
        for (int e = 0; e < 8; ++e) wtot[wave][e] = incl[e];
    __syncthreads();
    int tot[8];
#pragma unroll
    for (int e = 0; e < 8; ++e) tot[e] = wtot[0][e] + wtot[1][e] + wtot[2][e] + wtot[3][e];
    int waveoff = 0;
    for (int w = 0; w < 4; ++w) if (w < wave) waveoff += wtot[w][E];
    int offE = 0;
#pragma unroll
    for (int e = 0; e < 8; ++e) if (e < E) offE += tot[e];
    int rank = offE + waveoff + (incl[E] - c8[E]);
#pragma unroll
    for (int k = 0; k < 32; ++k) {
        if ((ev[k] & 7) == E) {
            int p = tid * 32 + k;
            elist[rank] = p >> 1;
            tslot[p] = rank;
            ++rank;
        }
    }
    if (tid == 0) { cnt[E] = tot[E]; off[E] = offE; }
}

// ---------------- flash attention, BQ=64, transposed-S, T14 + T2 swizzle + balanced qt ----------------
__global__ __launch_bounds__(256, 4) void attn_flash(const u16* __restrict__ proj,
    const u16* __restrict__ kc, const u16* __restrict__ vt, u16* __restrict__ ctx)
{
    const int qidx = blockIdx.x >> 5;
    const int qt = (qidx < 8) ? (31 - qidx) : (qidx < 16) ? (qidx - 8)
                 : (qidx < 24) ? (39 - qidx) : (qidx - 16);
    const int bh = blockIdx.x & 31;
    const int b = bh >> 4, h = bh & 15;
    const int q0 = qt * 64;
    const int tid = threadIdx.x, lane = tid & 63, wave = tid >> 6;
    const int quad = lane >> 4, rr = lane & 15, q8 = quad * 8;
    const int wm2 = wave * 16;

    __shared__ u16 Ks[64 * 128];   // [key][d], XOR-swizzled cols
    __shared__ u16 Ps[64 * 64];    // [qrow][key], XOR-swizzled cols, wave-private rows

    const long tbase = (long)b * S_ + q0;
    short8 qf[4];
#pragma unroll
    for (int d0 = 0; d0 < 4; ++d0)
        qf[d0] = *(const short8*)&proj[(tbase + wm2 + rr) * 2688 + h * 128 + d0 * 32 + q8];

    f32x4 accO[4];                 // O^T: [vi], lane: vd=vi*16+quad*4+rg, qrow=rr
    float m_i = -3e38f, l_i = 0.f;
#pragma unroll
    for (int vi = 0; vi < 4; ++vi)
#pragma unroll
        for (int rg = 0; rg < 4; ++rg) accO[vi][rg] = 0.f;
    const float sc = 0.08838834764831845f * 1.4426950408889634f;

    // staging geometry: thread owns rows srow0, srow0+32, 16B granule sg (logical)
    const int srow0 = tid >> 3, sg = tid & 7;
    const int swz = sg ^ (srow0 & 7);                    // swizzled granule
    const u16* kcp = kc   + ((long)b * S_ + srow0) * 1024 + h * 64 + sg * 8;
    const u16* krp = proj + ((long)b * S_ + srow0) * 2688 + 2560 + sg * 8;
    const u16* vbase = vt + (size_t)(h * 64 + rr) * 4096 + b * 2048 + q8;
    const int rg7 = rr & 7;
    int rdcol[4];
#pragma unroll
    for (int d0 = 0; d0 < 4; ++d0) rdcol[d0] = ((d0 * 4 + quad) ^ rg7) * 8;
    const int prcol0 = (((quad * 16) ^ (rg7 << 4)) >> 1);        // Ps read col, kc0=0
    const int prcol1 = (((64 + quad * 16) ^ (rg7 << 4)) >> 1);   // Ps read col, kc0=32

    const int nkt = qt + 1;
    // prologue: load tile 0 staging into regs
    short8 rk0 = *(const short8*)(kcp);
    short8 rk1 = *(const short8*)(kcp + 32 * 1024);
    short8 rm0 = *(const short8*)(krp);
    short8 rm1 = *(const short8*)(krp + (size_t)32 * 2688);

    for (int kt = 0; kt < nkt; ++kt) {
        const int k0 = kt * 64;
        // write current tile to LDS, swizzled (waits only on this tile's loads)
        *(short8*)&Ks[srow0 * 128 + swz * 8]             = rk0;
        *(short8*)&Ks[(srow0 + 32) * 128 + swz * 8]      = rk1;
        *(short8*)&Ks[srow0 * 128 + 64 + swz * 8]        = rm0;
        *(short8*)&Ks[(srow0 + 32) * 128 + 64 + swz * 8] = rm1;
        __syncthreads();

        // T14: issue next tile's staging loads now; consumed at next iter's write
        const size_t k0s = (kt + 1 < nkt) ? (size_t)(k0 + 64) : 0;   // clamp (safe dummy)
        short8 nk0 = *(const short8*)(kcp + k0s * 1024);
        short8 nk1 = *(const short8*)(kcp + k0s * 1024 + 32 * 1024);
        short8 nm0 = *(const short8*)(krp + k0s * 2688);
        short8 nm1 = *(const short8*)(krp + k0s * 2688 + (size_t)32 * 2688);

        // S^T = K·Q^T (swizzled Ks reads)
        f32x4 accS[4];
#pragma unroll
        for (int ki = 0; ki < 4; ++ki)
#pragma unroll
            for (int rg = 0; rg < 4; ++rg) accS[ki][rg] = 0.f;
        __builtin_amdgcn_s_setprio(1);
#pragma unroll
        for (int d0 = 0; d0 < 4; ++d0) {
            short8 kf[4];
#pragma unroll
            for (int ki = 0; ki < 4; ++ki) kf[ki] = *(const short8*)&Ks[(ki * 16 + rr) * 128 + rdcol[d0]];
#pragma unroll
            for (int ki = 0; ki < 4; ++ki) accS[ki] = MFMA(kf[ki], qf[d0], accS[ki]);
        }
        __builtin_amdgcn_s_setprio(0);
        __syncthreads();   // all waves done reading Ks -> next iter may overwrite

        // V fragments direct from global, issued early to hide under softmax
        short8 vf0[4], vf1[4];
#pragma unroll
        for (int vi = 0; vi < 4; ++vi) {
            vf0[vi] = *(const short8*)(vbase + (size_t)vi * 16 * 4096 + k0);
            vf1[vi] = *(const short8*)(vbase + (size_t)vi * 16 * 4096 + k0 + 32);
        }

        // softmax (masking only on the diagonal tile; block-uniform branch)
        float mx = -3e38f;
        if (kt == qt) {
            const int qg = q0 + wm2 + rr;
#pragma unroll
            for (int ki = 0; ki < 4; ++ki)
#pragma unroll
                for (int rg = 0; rg < 4; ++rg) {
                    float w = accS[ki][rg] * sc;
                    if (k0 + ki * 16 + quad * 4 + rg > qg) w = -1e30f;
                    accS[ki][rg] = w;
                    mx = fmaxf(mx, w);
                }
        } else {
#pragma unroll
            for (int ki = 0; ki < 4; ++ki)
#pragma unroll
                for (int rg = 0; rg < 4; ++rg) {
                    float w = accS[ki][rg] * sc;
                    accS[ki][rg] = w;
                    mx = fmaxf(mx, w);
                }
        }
        mx = fmaxf(mx, __shfl_xor(mx, 16));
        mx = fmaxf(mx, __shfl_xor(mx, 32));
        if (__any(mx > m_i)) {                 // rescale only when some row's max grew (exact)
            float mnew = fmaxf(m_i, mx);
            float alpha = exp2f(m_i - mnew);
            m_i = mnew;
            l_i *= alpha;
#pragma unroll
            for (int vi = 0; vi < 4; ++vi)
#pragma unroll
                for (int rg = 0; rg < 4; ++rg) accO[vi][rg] *= alpha;
        }
        float ps = 0.f;
#pragma unroll
        for (int ki = 0; ki < 4; ++ki) {
            float p0 = exp2f(accS[ki][0] - m_i);
            float p1 = exp2f(accS[ki][1] - m_i);
            float p2 = exp2f(accS[ki][2] - m_i);
            float p3 = exp2f(accS[ki][3] - m_i);
            ps += (p0 + p1) + (p2 + p3);
            u32x2 pk; pk[0] = cvtpk(p0, p1); pk[1] = cvtpk(p2, p3);
            *(u32x2*)&Ps[(wm2 + rr) * 64 + ((((ki * 32 + quad * 8) ^ (rg7 << 4)) >> 1))] = pk;
        }
        ps += __shfl_xor(ps, 16);
        ps += __shfl_xor(ps, 32);
        l_i += ps;

        // O^T += V^T · P^T (Ps rows wave-private: in-wave lgkmcnt ordering only)
        short8 pf0 = *(const short8*)&Ps[(wm2 + rr) * 64 + prcol0];
        short8 pf1 = *(const short8*)&Ps[(wm2 + rr) * 64 + prcol1];
        __builtin_amdgcn_s_setprio(1);
#pragma unroll
        for (int vi = 0; vi < 4; ++vi) accO[vi] = MFMA(vf0[vi], pf0, accO[vi]);
#pragma unroll
        for (int vi = 0; vi < 4; ++vi) accO[vi] = MFMA(vf1[vi], pf1, accO[vi]);
        __builtin_amdgcn_s_setprio(0);

        rk0 = nk0; rk1 = nk1; rm0 = nm0; rm1 = nm1;
    }
    // epilogue: ctx[t][h*64+vd] = O^T/l, packed 8B stores
    {
        float linv = 1.f / l_i;
        long t = tbase + wm2 + rr;
#pragma unroll
        for (int vi = 0; vi < 4; ++vi) {
            u32x2 pk;
            pk[0] = pack2(accO[vi][0] * linv, accO[vi][1] * linv);
            pk[1] = pack2(accO[vi][2] * linv, accO[vi][3] * linv);
            *(u32x2*)&ctx[t * 1024 + h * 64 + vi * 16 + quad * 4] = pk;
        }
    }
}

// ---------------- final (float4 vectorized): out = x_mid + w0*rout[s0] + w1*rout[s1] ----------------
__global__ __launch_bounds__(256) void final_kernel(const float* __restrict__ xm,
    const u16* __restrict__ rout, const int* __restrict__ tok_slot,
    const float* __restrict__ tok_w, float* __restrict__ out)
{
    long i = ((long)blockIdx.x * 256 + threadIdx.x) * 4;
    int t = (int)(i >> 10), d = (int)(i & 1023);
    int s0 = tok_slot[2 * t], s1 = tok_slot[2 * t + 1];
    float w0 = tok_w[2 * t], w1 = tok_w[2 * t + 1];
    f32x4 xv = *(const f32x4*)&xm[i];
    u32x2 r0 = *(const u32x2*)&rout[(long)s0 * 1024 + d];
    u32x2 r1 = *(const u32x2*)&rout[(long)s1 * 1024 + d];
    f32x4 o;
    o[0] = xv[0] + w0 * b2f((u16)(r0[0] & 0xffffu)) + w1 * b2f((u16)(r1[0] & 0xffffu));
    o[1] = xv[1] + w0 * b2f((u16)(r0[0] >> 16))     + w1 * b2f((u16)(r1[0] >> 16));
    o[2] = xv[2] + w0 * b2f((u16)(r0[1] & 0xffffu)) + w1 * b2f((u16)(r1[1] & 0xffffu));
    o[3] = xv[3] + w0 * b2f((u16)(r0[1] >> 16))     + w1 * b2f((u16)(r1[1] >> 16));
    *(f32x4*)&out[i] = o;
}

// ---------------- workspace layout (bytes); peak ~108.2 MB ----------------
#define OFF_XMID   0UL            // f32 4096x1024 (16.78M), lives whole call
#define OFF_H      16777216UL     // h -> h2, bf16 4096x1024 (8.39M)
#define OFF_PROJ   25165824UL     // proj 4096x2688 (22.02M); phase2: wgu_t 10x1Mx2B
#define OFF_WGU    25165824UL
#define OFF_KC     47185920UL     // kc 4096x1024 (8.39M); phase2: wd_t 10x0.5Mx2B
#define OFF_WD     47185920UL
#define OFF_VT     55574528UL     // vt 1024x4096 (8.39M), dead after attn
#define OFF_GUR    57671680UL     // act_r 8192x512 bf16 (8.39M)
#define OFF_CTX    63963136UL     // ctx 4096x1024 (8.39M)
#define OFF_WATT   72351744UL     // wqkv 5.51M, wuk 1.05M, wuv 1.05M, wo 2.10M
#define OFF_ROUT   74448896UL     // rout 8192x1024 bf16 (16.78M), overlays attn weights
#define OFF_GUS    91226112UL     // act_s 4096x1024 bf16 (8.39M)
#define OFF_TOKE   108003328UL
#define OFF_TOKW   108036096UL
#define OFF_TSLOT  108068864UL
#define OFF_ELIST  108101632UL
#define OFF_META   108134400UL

extern "C" void kernel_launch(void* const* d_in, const int* in_sizes, int n_in,
                              void* d_out, int out_size, void* d_ws, size_t ws_size,
                              hipStream_t stream)
{
    const float* x       = (const float*)d_in[0];
    const float* w_q     = (const float*)d_in[2];
    const float* w_dkv   = (const float*)d_in[3];
    const float* w_uk    = (const float*)d_in[4];
    const float* w_uv    = (const float*)d_in[5];
    const float* w_kr    = (const float*)d_in[6];
    const float* w_o     = (const float*)d_in[7];
    const float* attn_nw = (const float*)d_in[8];
    const float* mlp_nw  = (const float*)d_in[9];
    const float* gate_w  = (const float*)d_in[10];
    const float* wr_gate = (const float*)d_in[11];
    const float* wr_up   = (const float*)d_in[12];
    const float* wr_down = (const float*)d_in[13];
    const float* ws_gate = (const float*)d_in[14];
    const float* ws_up   = (const float*)d_in[15];
    const float* ws_down = (const float*)d_in[16];
    float* out = (float*)d_out;

    char* W = (char*)d_ws;
    float* x_mid = (float*)(W + OFF_XMID);
    u16* h      = (u16*)(W + OFF_H);
    u16* h2     = (u16*)(W + OFF_H);
    u16* proj   = (u16*)(W + OFF_PROJ);
    u16* wgu_t  = (u16*)(W + OFF_WGU);
    u16* kc     = (u16*)(W + OFF_KC);
    u16* wd_t   = (u16*)(W + OFF_WD);
    u16* vt     = (u16*)(W + OFF_VT);
    u16* act_r  = (u16*)(W + OFF_GUR);
    u16* ctx    = (u16*)(W + OFF_CTX);
    u16* wqkv_t = (u16*)(W + OFF_WATT);
    u16* wuk_t  = wqkv_t + 2688 * 1024;
    u16* wuv_t  = wuk_t + 1024 * 512;
    u16* wo_t   = wuv_t + 1024 * 512;
    u16* rout   = (u16*)(W + OFF_ROUT);
    u16* act_s  = (u16*)(W + OFF_GUS);
    int*   tok_e = (int*)(W + OFF_TOKE);
    float* tok_w = (float*)(W + OFF_TOKW);
    int*   tslot = (int*)(W + OFF_TSLOT);
    int*   elist = (int*)(W + OFF_ELIST);
    int*   meta  = (int*)(W + OFF_META);
    int* cnt = meta, * off = meta + 8;

    dim3 tb(32, 8);
    // attn weights, 2 merged launches
    transpose_attn_a<<<dim3(82, 32), tb, 0, stream>>>(w_q, w_dkv, w_kr, wqkv_t);
    transpose_attn_b<<<dim3(32, 64), tb, 0, stream>>>(w_uk, w_uv, w_o, wuk_t, wuv_t, wo_t);

    // attention path (RoPE fused into qkv GEMM epilogue)
    rmsnorm_wave<<<T_ / 4, 256, 0, stream>>>(x, attn_nw, h);
    gemm_k<<<dim3(21, 32), 256, 0, stream>>>(h, 1024, wqkv_t, 1024, proj, 2688, 1024, 1, nullptr, 1);
    gemm_dual<<<dim3(32, 32, 2), 256, 0, stream>>>(
        proj + 2048, 2688, wuk_t, 512, kc, 1024, 8, 32,
        wuv_t, 512, proj + 2048, 2688, vt, 4096, 32, 8);
    attn_flash<<<1024, 256, 0, stream>>>(proj, kc, vt, ctx);
    gemm_k<<<dim3(8, 32), 256, 0, stream>>>(ctx, 1024, wo_t, 1024, x_mid, 1024, 1024, 3, x, 0);

    // MoE weights, ONE merged launch (overlays proj/kc after attn)
    transpose_moe<<<dim3(32, 32, 30), tb, 0, stream>>>(wr_gate, wr_up, ws_gate, ws_up,
                                                       wr_down, ws_down, wgu_t, wd_t);

    // MoE path: fused rmsnorm+gate -> atomic-free routing
    rmsnorm_gate_fused<<<T_ / 4, 256, 0, stream>>>(x_mid, mlp_nw, gate_w, h2, tok_e, tok_w);
    moe_route<<<8, 256, 0, stream>>>(tok_e, cnt, off, elist, tslot);
    // gate|up (+fused silu) for routed + shared in ONE launch; down in ONE launch
    gemm_guall<<<dim3(8, 32, 10), 256, 0, stream>>>(h2, wgu_t, act_r, act_s, cnt, off, elist);
    gemm_downall<<<dim3(8, 32, 9), 256, 0, stream>>>(act_r, act_s, wd_t, rout, x_mid, cnt, off);
    final_kernel<<<(T_ * D_) / 1024, 256, 0, stream>>>(x_mid, rout, tslot, tok_w, out);
}

// Round 10
// 512.929 us; speedup vs baseline: 1.0751x; 1.0751x over previous
//
#include <hip/hip_runtime.h>
#include <hip/hip_bf16.h>
#include <stdint.h>

typedef unsigned short u16;
typedef __attribute__((ext_vector_type(8))) short short8;
typedef __attribute__((ext_vector_type(4))) float f32x4;
typedef __attribute__((ext_vector_type(4))) int i32x4;
typedef __attribute__((ext_vector_type(2))) unsigned int u32x2;

#define B_    2
#define S_    2048
#define D_    1024
#define H_    16
#define T_    (B_*S_)

static __device__ __forceinline__ float b2f(u16 h) { return __uint_as_float(((uint32_t)h) << 16); }
static __device__ __forceinline__ u16 f2b(float f) {
    uint32_t u = __float_as_uint(f);
    u += 0x7fffu + ((u >> 16) & 1u);          // RNE
    return (u16)(u >> 16);
}
static __device__ __forceinline__ uint32_t pack2(float a, float b) {
    return (uint32_t)f2b(a) | ((uint32_t)f2b(b) << 16);
}
static __device__ __forceinline__ uint32_t cvtpk(float a, float b) {
    uint32_t r;
    asm("v_cvt_pk_bf16_f32 %0, %1, %2" : "=v"(r) : "v"(a), "v"(b));
    return r;
}
#define MFMA(a,b,c) __builtin_amdgcn_mfma_f32_16x16x32_bf16(a,b,c,0,0,0)

// async global->LDS, 16B per lane; lds dest = wave-uniform base + lane*16B
static __device__ __forceinline__ void gl2lds16(const void* g, void* l) {
    __builtin_amdgcn_global_load_lds((const __attribute__((address_space(1))) void*)g,
                                     (__attribute__((address_space(3))) void*)l, 16, 0, 0);
}

// ---------------- transpose cores ----------------
static __device__ __forceinline__ void tr_body(const float* __restrict__ ip,
    u16* __restrict__ op, int K, int N, int k0, int n0, float (*tile)[33])
{
    int tx = threadIdx.x, ty = threadIdx.y;   // 32 x 8
#pragma unroll
    for (int i = 0; i < 4; ++i) {
        int k = k0 + ty + 8 * i, n = n0 + tx;
        tile[ty + 8 * i][tx] = (k < K && n < N) ? ip[(long)k * N + n] : 0.f;
    }
    __syncthreads();
#pragma unroll
    for (int i = 0; i < 4; ++i) {
        int n = n0 + ty + 8 * i, k = k0 + tx;
        if (n < N && k < K) op[(long)n * K + k] = f2b(tile[tx][ty + 8 * i]);
    }
}

// gate|up transpose with interleave-permuted destination rows:
// src col n (0..511), dest row = 128*(n>>6) + 64*((n>>5)&1) + (is_up?32:0) + (n&31)
// -> each 128-row block of wgu_t holds gate[64t..64t+63] and up[same cols],
//    paired within-lane in the GEMM epilogue (ni <-> ni+2).
static __device__ __forceinline__ void tr_body_perm(const float* __restrict__ ip,
    u16* __restrict__ op, int k0, int n0, int is_up, float (*tile)[33])
{
    int tx = threadIdx.x, ty = threadIdx.y;   // 32 x 8; K=1024, N=512
#pragma unroll
    for (int i = 0; i < 4; ++i) {
        int k = k0 + ty + 8 * i, n = n0 + tx;
        tile[ty + 8 * i][tx] = ip[(long)k * 512 + n];
    }
    __syncthreads();
#pragma unroll
    for (int i = 0; i < 4; ++i) {
        int n = n0 + ty + 8 * i, k = k0 + tx;
        int nr = 128 * (n >> 6) + 64 * ((n >> 5) & 1) + (is_up ? 32 : 0) + (n & 31);
        op[(long)nr * 1024 + k] = f2b(tile[tx][ty + 8 * i]);
    }
}

// attn weights group A: w_q | w_dkv | w_kr (all K=1024), grid (82, 32)
__global__ __launch_bounds__(256) void transpose_attn_a(const float* __restrict__ wq,
    const float* __restrict__ wdkv, const float* __restrict__ wkr, u16* __restrict__ out)
{
    __shared__ float tile[32][33];
    int bx = blockIdx.x;
    const float* in; u16* op; int N; int n0;
    if (bx < 64)      { in = wq;   op = out;             N = 2048; n0 = bx * 32; }
    else if (bx < 80) { in = wdkv; op = out + 2048*1024; N = 512;  n0 = (bx-64) * 32; }
    else              { in = wkr;  op = out + 2560*1024; N = 64;   n0 = (bx-80) * 32; }
    tr_body(in, op, 1024, N, blockIdx.y * 32, n0, tile);
}

// attn weights group B: w_uk | w_uv | w_o (N=1024), grid (32, 64)
__global__ __launch_bounds__(256) void transpose_attn_b(const float* __restrict__ wuk,
    const float* __restrict__ wuv, const float* __restrict__ wo,
    u16* __restrict__ uk_t, u16* __restrict__ uv_t, u16* __restrict__ wo_t)
{
    __shared__ float tile[32][33];
    int by = blockIdx.y;
    const float* in; u16* op; int K; int k0;
    if (by < 16)      { in = wuk; op = uk_t; K = 512;  k0 = by * 32; }
    else if (by < 32) { in = wuv; op = uv_t; K = 512;  k0 = (by-16) * 32; }
    else              { in = wo;  op = wo_t; K = 1024; k0 = (by-32) * 32; }
    tr_body(in, op, K, 1024, k0, blockIdx.x * 32, tile);
}

// MoE gate|up weights (permuted rows), grid (16, 32, 20)
__global__ __launch_bounds__(256) void transpose_moe_gu(const float* __restrict__ wr_gate,
    const float* __restrict__ wr_up, const float* __restrict__ ws_gate,
    const float* __restrict__ ws_up, u16* __restrict__ wgu_t)
{
    __shared__ float tile[32][33];
    int z = blockIdx.z;
    const float* in; u16* op; int is_up;
    if (z < 8)       { in = wr_gate + (long)z * 524288;      op = wgu_t + (long)z * 1048576;      is_up = 0; }
    else if (z < 16) { in = wr_up   + (long)(z-8) * 524288;  op = wgu_t + (long)(z-8) * 1048576;  is_up = 1; }
    else if (z < 18) { in = ws_gate + (long)(z-16) * 524288; op = wgu_t + (long)(z-8) * 1048576;  is_up = 0; }
    else             { in = ws_up   + (long)(z-18) * 524288; op = wgu_t + (long)(z-10) * 1048576; is_up = 1; }
    tr_body_perm(in, op, blockIdx.y * 32, blockIdx.x * 32, is_up, tile);
}

// MoE down weights: wr_down/ws_down, grid (32, 16, 10)
__global__ __launch_bounds__(256) void transpose_moe_down(const float* __restrict__ wr_down,
    const float* __restrict__ ws_down, u16* __restrict__ wd_t)
{
    __shared__ float tile[32][33];
    int z = blockIdx.z;
    const float* in = (z < 8) ? wr_down + (long)z * 524288 : ws_down + (long)(z-8) * 524288;
    u16* op = wd_t + (long)z * 524288;
    tr_body(in, op, 512, 1024, blockIdx.y * 32, blockIdx.x * 32, tile);
}

// ---------------- MFMA GEMM, depth-2 pipelined (3 LDS bufs, counted vmcnt) ----------------
// mode: 1 = bf16 store, 2 = f32 +=, 3 = f32 store of (v + resid)
__global__ __launch_bounds__(256) void gemm_k(const u16* __restrict__ A, long lda,
    const u16* __restrict__ Bt, long ldb, void* __restrict__ Cv, long ldc, int K,
    int mode, const float* __restrict__ resid)
{
    __shared__ u16 As[3][128 * 32];
    __shared__ u16 Bs[3][128 * 32];
    const int tid = threadIdx.x, lane = tid & 63, wave = tid >> 6;
    const int wm = (wave & 1) * 64, wn = (wave >> 1) * 64;
    const int quad = lane >> 4, rr = lane & 15, q8 = quad * 8;
    const long row0 = (long)blockIdx.y * 128, col0 = (long)blockIdx.x * 128;
    f32x4 acc[4][4];
#pragma unroll
    for (int i = 0; i < 4; ++i)
#pragma unroll
        for (int j = 0; j < 4; ++j)
#pragma unroll
            for (int c = 0; c < 4; ++c) acc[i][j][c] = 0.f;
    const int band = wave * 32;
    const u16* ga = A + (row0 + band + (lane >> 2)) * lda + (lane & 3) * 8;
    const u16* gb = Bt + (col0 + band + (lane >> 2)) * ldb + (lane & 3) * 8;
    const int lo = band * 32;
    const int nt = K >> 5;
#define STG(bi, k0s) do { \
    gl2lds16(ga + (k0s), &As[bi][lo]); \
    gl2lds16(ga + (k0s) + 16 * lda, &As[bi][lo + 512]); \
    gl2lds16(gb + (k0s), &Bs[bi][lo]); \
    gl2lds16(gb + (k0s) + 16 * ldb, &Bs[bi][lo + 512]); } while (0)
    STG(0, 0);
    STG(1, 32);
    asm volatile("s_waitcnt vmcnt(4)" ::: "memory");
    __builtin_amdgcn_s_barrier();
    int cur = 0, nx2 = 2;
    for (int t = 0; t < nt; ++t) {
        const bool more = (t + 2 < nt);
        if (more) STG(nx2, (t + 2) * 32);
        short8 af[4], bf[4];
#pragma unroll
        for (int mi = 0; mi < 4; ++mi) af[mi] = *(const short8*)&As[cur][(wm + mi * 16 + rr) * 32 + q8];
#pragma unroll
        for (int ni = 0; ni < 4; ++ni) bf[ni] = *(const short8*)&Bs[cur][(wn + ni * 16 + rr) * 32 + q8];
#pragma unroll
        for (int mi = 0; mi < 4; ++mi)
#pragma unroll
            for (int ni = 0; ni < 4; ++ni)
                acc[mi][ni] = MFMA(af[mi], bf[ni], acc[mi][ni]);
        if (more) asm volatile("s_waitcnt vmcnt(4)" ::: "memory");
        else      asm volatile("s_waitcnt vmcnt(0)" ::: "memory");
        __builtin_amdgcn_s_barrier();
        cur = (cur == 2) ? 0 : cur + 1;
        nx2 = (nx2 == 2) ? 0 : nx2 + 1;
    }
#undef STG
#pragma unroll
    for (int mi = 0; mi < 4; ++mi)
#pragma unroll
        for (int ni = 0; ni < 4; ++ni)
#pragma unroll
            for (int rg = 0; rg < 4; ++rg) {
                long r = row0 + wm + mi * 16 + quad * 4 + rg;
                long c = col0 + wn + ni * 16 + rr;
                float v = acc[mi][ni][rg];
                if (mode == 1)      ((u16*)Cv)[r * ldc + c] = f2b(v);
                else if (mode == 2) ((float*)Cv)[r * ldc + c] += v;
                else                ((float*)Cv)[r * ldc + c] = v + resid[r * 1024 + c];
            }
}

// ---------------- dual independent GEMM (both K=512, bf16 store), z picks desc ----------------
__global__ __launch_bounds__(256) void gemm_dual(
    const u16* __restrict__ A0, long lda0, const u16* __restrict__ B0, long ldb0, u16* __restrict__ C0, long ldc0, int nx0, int ny0,
    const u16* __restrict__ A1, long lda1, const u16* __restrict__ B1, long ldb1, u16* __restrict__ C1, long ldc1, int nx1, int ny1)
{
    const int z = blockIdx.z;
    if ((int)blockIdx.x >= (z ? nx1 : nx0) || (int)blockIdx.y >= (z ? ny1 : ny0)) return;
    const u16* A  = z ? A1 : A0;  const long lda = z ? lda1 : lda0;
    const u16* Bt = z ? B1 : B0;  const long ldb = z ? ldb1 : ldb0;
    u16* C = z ? C1 : C0;         const long ldc = z ? ldc1 : ldc0;
    __shared__ u16 As[3][128 * 32];
    __shared__ u16 Bs[3][128 * 32];
    const int tid = threadIdx.x, lane = tid & 63, wave = tid >> 6;
    const int wm = (wave & 1) * 64, wn = (wave >> 1) * 64;
    const int quad = lane >> 4, rr = lane & 15, q8 = quad * 8;
    const long row0 = (long)blockIdx.y * 128, col0 = (long)blockIdx.x * 128;
    f32x4 acc[4][4];
#pragma unroll
    for (int i = 0; i < 4; ++i)
#pragma unroll
        for (int j = 0; j < 4; ++j)
#pragma unroll
            for (int c = 0; c < 4; ++c) acc[i][j][c] = 0.f;
    const int band = wave * 32;
    const u16* ga = A + (row0 + band + (lane >> 2)) * lda + (lane & 3) * 8;
    const u16* gb = Bt + (col0 + band + (lane >> 2)) * ldb + (lane & 3) * 8;
    const int lo = band * 32;
    const int nt = 16;   // K=512
#define STG(bi, k0s) do { \
    gl2lds16(ga + (k0s), &As[bi][lo]); \
    gl2lds16(ga + (k0s) + 16 * lda, &As[bi][lo + 512]); \
    gl2lds16(gb + (k0s), &Bs[bi][lo]); \
    gl2lds16(gb + (k0s) + 16 * ldb, &Bs[bi][lo + 512]); } while (0)
    STG(0, 0);
    STG(1, 32);
    asm volatile("s_waitcnt vmcnt(4)" ::: "memory");
    __builtin_amdgcn_s_barrier();
    int cur = 0, nx2 = 2;
    for (int t = 0; t < nt; ++t) {
        const bool more = (t + 2 < nt);
        if (more) STG(nx2, (t + 2) * 32);
        short8 af[4], bf[4];
#pragma unroll
        for (int mi = 0; mi < 4; ++mi) af[mi] = *(const short8*)&As[cur][(wm + mi * 16 + rr) * 32 + q8];
#pragma unroll
        for (int ni = 0; ni < 4; ++ni) bf[ni] = *(const short8*)&Bs[cur][(wn + ni * 16 + rr) * 32 + q8];
#pragma unroll
        for (int mi = 0; mi < 4; ++mi)
#pragma unroll
            for (int ni = 0; ni < 4; ++ni)
                acc[mi][ni] = MFMA(af[mi], bf[ni], acc[mi][ni]);
        if (more) asm volatile("s_waitcnt vmcnt(4)" ::: "memory");
        else      asm volatile("s_waitcnt vmcnt(0)" ::: "memory");
        __builtin_amdgcn_s_barrier();
        cur = (cur == 2) ? 0 : cur + 1;
        nx2 = (nx2 == 2) ? 0 : nx2 + 1;
    }
#undef STG
#pragma unroll
    for (int mi = 0; mi < 4; ++mi)
#pragma unroll
        for (int ni = 0; ni < 4; ++ni)
#pragma unroll
            for (int rg = 0; rg < 4; ++rg) {
                long r = row0 + wm + mi * 16 + quad * 4 + rg;
                long c = col0 + wn + ni * 16 + rr;
                C[r * ldc + c] = f2b(acc[mi][ni][rg]);
            }
}

// ---------------- gate|up + FUSED SiLU for ALL experts ----------------
// z<8 routed (gathered), z=8,9 shared. B rows interleaved (gate j at row 128t+64h+j,
// up j at +32) so silu pairs are within-lane: g=acc[mi][ni], u=acc[mi][ni+2], ni<2.
// Output: act_r[slot][512] (routed), act_s[token][1024] (shared: e8 cols 0-511, e9 512-1023).
__global__ __launch_bounds__(256) void gemm_guall(const u16* __restrict__ H2,
    const u16* __restrict__ BtAll, u16* __restrict__ act_r, u16* __restrict__ act_s,
    const int* __restrict__ cnt, const int* __restrict__ off, const int* __restrict__ elist)
{
    const int e = blockIdx.z;
    const bool sh = (e >= 8);
    const int cntE = sh ? 4096 : cnt[e];
    const int offE = sh ? 0 : off[e];
    const int m0 = blockIdx.y * 128;
    if (m0 >= cntE) return;
    const u16* Bt = BtAll + (long)e * 1048576;
    __shared__ u16 As[3][128 * 32];
    __shared__ u16 Bs[3][128 * 32];
    const int tid = threadIdx.x, lane = tid & 63, wave = tid >> 6;
    const int wm = (wave & 1) * 64, wn = (wave >> 1) * 64;
    const int quad = lane >> 4, rr = lane & 15, q8 = quad * 8;
    f32x4 acc[4][4];
#pragma unroll
    for (int i = 0; i < 4; ++i)
#pragma unroll
        for (int j = 0; j < 4; ++j)
#pragma unroll
            for (int c = 0; c < 4; ++c) acc[i][j][c] = 0.f;
    const int band = wave * 32;
    int r0 = m0 + band + (lane >> 2);
    int r1 = r0 + 16;
    int tok0, tok1;
    if (sh) { tok0 = r0; tok1 = r1; }
    else {
        tok0 = elist[offE + (r0 < cntE ? r0 : cntE - 1)];
        tok1 = elist[offE + (r1 < cntE ? r1 : cntE - 1)];
    }
    const u16* ga0 = H2 + (long)tok0 * 1024 + (lane & 3) * 8;
    const u16* ga1 = H2 + (long)tok1 * 1024 + (lane & 3) * 8;
    const u16* gb = Bt + ((long)blockIdx.x * 128 + band + (lane >> 2)) * 1024L + (lane & 3) * 8;
    const int lo = band * 32;
#define STG(bi, k0s) do { \
    gl2lds16(ga0 + (k0s), &As[bi][lo]); \
    gl2lds16(ga1 + (k0s), &As[bi][lo + 512]); \
    gl2lds16(gb + (k0s), &Bs[bi][lo]); \
    gl2lds16(gb + (k0s) + 16 * 1024, &Bs[bi][lo + 512]); } while (0)
    const int nt = 32;   // K=1024
    STG(0, 0);
    STG(1, 32);
    asm volatile("s_waitcnt vmcnt(4)" ::: "memory");
    __builtin_amdgcn_s_barrier();
    int cur = 0, nx2 = 2;
    for (int t = 0; t < nt; ++t) {
        const bool more = (t + 2 < nt);
        if (more) STG(nx2, (t + 2) * 32);
        short8 af[4], bf[4];
#pragma unroll
        for (int mi = 0; mi < 4; ++mi) af[mi] = *(const short8*)&As[cur][(wm + mi * 16 + rr) * 32 + q8];
#pragma unroll
        for (int ni = 0; ni < 4; ++ni) bf[ni] = *(const short8*)&Bs[cur][(wn + ni * 16 + rr) * 32 + q8];
#pragma unroll
        for (int mi = 0; mi < 4; ++mi)
#pragma unroll
            for (int ni = 0; ni < 4; ++ni)
                acc[mi][ni] = MFMA(af[mi], bf[ni], acc[mi][ni]);
        if (more) asm volatile("s_waitcnt vmcnt(4)" ::: "memory");
        else      asm volatile("s_waitcnt vmcnt(0)" ::: "memory");
        __builtin_amdgcn_s_barrier();
        cur = (cur == 2) ? 0 : cur + 1;
        nx2 = (nx2 == 2) ? 0 : nx2 + 1;
    }
#undef STG
    // fused silu(g)*u epilogue, within-lane pairing; writes 512-wide act
#pragma unroll
    for (int mi = 0; mi < 4; ++mi)
#pragma unroll
        for (int ni = 0; ni < 2; ++ni)
#pragma unroll
            for (int rg = 0; rg < 4; ++rg) {
                int ml = wm + mi * 16 + quad * 4 + rg;
                if (m0 + ml >= cntE) continue;
                int cout = 64 * (int)blockIdx.x + 32 * (wn >> 6) + ni * 16 + rr;
                float g = acc[mi][ni][rg], u = acc[mi][ni + 2][rg];
                float val = g / (1.f + __expf(-g)) * u;
                if (sh) act_s[(long)(m0 + ml) * 1024 + (long)(e - 8) * 512 + cout] = f2b(val);
                else    act_r[(long)(offE + m0 + ml) * 512 + cout] = f2b(val);
            }
}

// ---------------- down for ALL: z<8 routed (K=512 -> rout bf16), z=8 shared fused (K=1024 -> x_mid +=) ----------------
// grid (8, 32, 9); act_r 512-wide, act_s 1024-wide
__global__ __launch_bounds__(256) void gemm_downall(const u16* __restrict__ act_r,
    const u16* __restrict__ act_s, const u16* __restrict__ WdAll, u16* __restrict__ rout,
    float* __restrict__ xmid, const int* __restrict__ cnt, const int* __restrict__ off)
{
    const int e = blockIdx.z;
    __shared__ u16 As[3][128 * 32];
    __shared__ u16 Bs[3][128 * 32];
    const int tid = threadIdx.x, lane = tid & 63, wave = tid >> 6;
    const int wm = (wave & 1) * 64, wn = (wave >> 1) * 64;
    const int quad = lane >> 4, rr = lane & 15, q8 = quad * 8;
    const long col0 = (long)blockIdx.x * 128;
    const int m0 = blockIdx.y * 128;
    const int band = wave * 32;
    const int lo = band * 32;
    f32x4 acc[4][4];
#pragma unroll
    for (int i = 0; i < 4; ++i)
#pragma unroll
        for (int j = 0; j < 4; ++j)
#pragma unroll
            for (int c = 0; c < 4; ++c) acc[i][j][c] = 0.f;
    if (e < 8) {
        const int cntE = cnt[e], offE = off[e];
        if (m0 >= cntE) return;
        const u16* Bt = WdAll + (long)e * 524288;
        int r0 = offE + m0 + band + (lane >> 2); if (r0 > 8191) r0 = 8191;
        int r1 = r0 + 16; if (r1 > 8191) r1 = 8191;
        const u16* ga0 = act_r + (long)r0 * 512 + (lane & 3) * 8;
        const u16* ga1 = act_r + (long)r1 * 512 + (lane & 3) * 8;
        const u16* gb = Bt + (col0 + band + (lane >> 2)) * 512L + (lane & 3) * 8;
#define STGR(bi, k0s) do { \
    gl2lds16(ga0 + (k0s), &As[bi][lo]); \
    gl2lds16(ga1 + (k0s), &As[bi][lo + 512]); \
    gl2lds16(gb + (k0s), &Bs[bi][lo]); \
    gl2lds16(gb + (k0s) + 16 * 512, &Bs[bi][lo + 512]); } while (0)
        const int nt = 16;   // K=512
        STGR(0, 0);
        STGR(1, 32);
        asm volatile("s_waitcnt vmcnt(4)" ::: "memory");
        __builtin_amdgcn_s_barrier();
        int cur = 0, nx2 = 2;
        for (int t = 0; t < nt; ++t) {
            const bool more = (t + 2 < nt);
            if (more) STGR(nx2, (t + 2) * 32);
            short8 af[4], bf[4];
#pragma unroll
            for (int mi = 0; mi < 4; ++mi) af[mi] = *(const short8*)&As[cur][(wm + mi * 16 + rr) * 32 + q8];
#pragma unroll
            for (int ni = 0; ni < 4; ++ni) bf[ni] = *(const short8*)&Bs[cur][(wn + ni * 16 + rr) * 32 + q8];
#pragma unroll
            for (int mi = 0; mi < 4; ++mi)
#pragma unroll
                for (int ni = 0; ni < 4; ++ni)
                    acc[mi][ni] = MFMA(af[mi], bf[ni], acc[mi][ni]);
            if (more) asm volatile("s_waitcnt vmcnt(4)" ::: "memory");
            else      asm volatile("s_waitcnt vmcnt(0)" ::: "memory");
            __builtin_amdgcn_s_barrier();
            cur = (cur == 2) ? 0 : cur + 1;
            nx2 = (nx2 == 2) ? 0 : nx2 + 1;
        }
#undef STGR
#pragma unroll
        for (int mi = 0; mi < 4; ++mi)
#pragma unroll
            for (int ni = 0; ni < 4; ++ni)
#pragma unroll
                for (int rg = 0; rg < 4; ++rg) {
                    int ml = wm + mi * 16 + quad * 4 + rg;
                    long c = col0 + wn + ni * 16 + rr;
                    if (m0 + ml < cntE)
                        rout[(long)(offE + m0 + ml) * 1024 + c] = f2b(acc[mi][ni][rg]);
                }
    } else {
        // shared fused down: x_mid += act8*wd8^T + act9*wd9^T (A = act_s 1024-wide)
        const u16* BtBase = WdAll + 8L * 524288;
        const long arow = m0 + band + (lane >> 2);
        const long brow = col0 + band + (lane >> 2);
#define STGS(bi, k0s) do { \
    const long boff = ((k0s) < 512) ? (long)(k0s) : (long)(524288 - 512 + (k0s)); \
    const u16* ga = act_s + arow * 1024 + (k0s) + (lane & 3) * 8; \
    const u16* gb = BtBase + brow * 512 + boff + (lane & 3) * 8; \
    gl2lds16(ga, &As[bi][lo]); \
    gl2lds16(ga + 16 * 1024, &As[bi][lo + 512]); \
    gl2lds16(gb, &Bs[bi][lo]); \
    gl2lds16(gb + 16 * 512, &Bs[bi][lo + 512]); } while (0)
        const int nt = 32;   // K=1024 equivalent
        STGS(0, 0);
        STGS(1, 32);
        asm volatile("s_waitcnt vmcnt(4)" ::: "memory");
        __builtin_amdgcn_s_barrier();
        int cur = 0, nx2 = 2;
        for (int t = 0; t < nt; ++t) {
            const bool more = (t + 2 < nt);
            if (more) STGS(nx2, (t + 2) * 32);
            short8 af[4], bf[4];
#pragma unroll
            for (int mi = 0; mi < 4; ++mi) af[mi] = *(const short8*)&As[cur][(wm + mi * 16 + rr) * 32 + q8];
#pragma unroll
            for (int ni = 0; ni < 4; ++ni) bf[ni] = *(const short8*)&Bs[cur][(wn + ni * 16 + rr) * 32 + q8];
#pragma unroll
            for (int mi = 0; mi < 4; ++mi)
#pragma unroll
                for (int ni = 0; ni < 4; ++ni)
                    acc[mi][ni] = MFMA(af[mi], bf[ni], acc[mi][ni]);
            if (more) asm volatile("s_waitcnt vmcnt(4)" ::: "memory");
            else      asm volatile("s_waitcnt vmcnt(0)" ::: "memory");
            __builtin_amdgcn_s_barrier();
            cur = (cur == 2) ? 0 : cur + 1;
            nx2 = (nx2 == 2) ? 0 : nx2 + 1;
        }
#undef STGS
#pragma unroll
        for (int mi = 0; mi < 4; ++mi)
#pragma unroll
            for (int ni = 0; ni < 4; ++ni)
#pragma unroll
                for (int rg = 0; rg < 4; ++rg) {
                    long r = m0 + wm + mi * 16 + quad * 4 + rg;
                    long c = col0 + wn + ni * 16 + rr;
                    xmid[r * 1024 + c] += acc[mi][ni][rg];
                }
    }
}

// ---------------- wave-per-token rmsnorm f32 -> bf16 (no barriers) ----------------
__global__ __launch_bounds__(256) void rmsnorm_wave(const float* __restrict__ x,
    const float* __restrict__ w, u16* __restrict__ out)
{
    const int t = blockIdx.x * 4 + (threadIdx.x >> 6);
    const int lane = threadIdx.x & 63;
    const float* xp = x + (size_t)t * D_;
    f32x4 v[4];
    float s = 0.f;
#pragma unroll
    for (int i = 0; i < 4; ++i) {
        v[i] = *(const f32x4*)&xp[lane * 4 + i * 256];
#pragma unroll
        for (int j = 0; j < 4; ++j) s += v[i][j] * v[i][j];
    }
#pragma unroll
    for (int o = 32; o > 0; o >>= 1) s += __shfl_xor(s, o);
    const float inv = rsqrtf(s * (1.f / D_) + 1e-6f);
    u16* op = out + (size_t)t * D_;
#pragma unroll
    for (int i = 0; i < 4; ++i) {
        const int d = lane * 4 + i * 256;
        f32x4 wv = *(const f32x4*)&w[d];
        u32x2 pk;
        pk[0] = pack2(v[i][0] * inv * wv[0], v[i][1] * inv * wv[1]);
        pk[1] = pack2(v[i][2] * inv * wv[2], v[i][3] * inv * wv[3]);
        *(u32x2*)&op[d] = pk;
    }
}

// ---------------- fused mlp-rmsnorm + gate: h2 + top2, wave-per-token, NO atomics ----------------
__global__ __launch_bounds__(256) void rmsnorm_gate_fused(const float* __restrict__ xm,
    const float* __restrict__ nw, const float* __restrict__ gw, u16* __restrict__ h2,
    int* __restrict__ tok_e, float* __restrict__ tok_w)
{
    const int t = blockIdx.x * 4 + (threadIdx.x >> 6);
    const int lane = threadIdx.x & 63;
    const float* xp = xm + (size_t)t * D_;
    f32x4 v[4];
    float s = 0.f;
#pragma unroll
    for (int i = 0; i < 4; ++i) {
        v[i] = *(const f32x4*)&xp[lane * 4 + i * 256];
#pragma unroll
        for (int j = 0; j < 4; ++j) s += v[i][j] * v[i][j];
    }
#pragma unroll
    for (int o = 32; o > 0; o >>= 1) s += __shfl_xor(s, o);
    const float inv = rsqrtf(s * (1.f / D_) + 1e-6f);
    u16* op = h2 + (size_t)t * D_;
    float part[8] = {0,0,0,0,0,0,0,0};
#pragma unroll
    for (int i = 0; i < 4; ++i) {
        const int d = lane * 4 + i * 256;
        f32x4 wv = *(const f32x4*)&nw[d];
        float hv[4];
#pragma unroll
        for (int j = 0; j < 4; ++j) hv[j] = v[i][j] * inv * wv[j];
        u32x2 pk;
        pk[0] = pack2(hv[0], hv[1]);
        pk[1] = pack2(hv[2], hv[3]);
        *(u32x2*)&op[d] = pk;
#pragma unroll
        for (int j = 0; j < 4; ++j) {
            const float* gp = gw + (size_t)(d + j) * 8;
#pragma unroll
            for (int e = 0; e < 8; ++e) part[e] += hv[j] * gp[e];
        }
    }
#pragma unroll
    for (int e = 0; e < 8; ++e)
#pragma unroll
        for (int o = 32; o > 0; o >>= 1) part[e] += __shfl_xor(part[e], o);
    if (lane == 0) {
        float mx = part[0];
#pragma unroll
        for (int e = 1; e < 8; ++e) mx = fmaxf(mx, part[e]);
        float p[8];
#pragma unroll
        for (int e = 0; e < 8; ++e) p[e] = __expf(part[e] - mx);
        int i0 = 0;
#pragma unroll
        for (int e = 1; e < 8; ++e) if (p[e] > p[i0]) i0 = e;
        int i1 = (i0 == 0) ? 1 : 0;
#pragma unroll
        for (int e = 0; e < 8; ++e) { if (e == i0) continue; if (p[e] > p[i1]) i1 = e; }
        float sw = p[i0] + p[i1];
        tok_e[2 * t] = i0;  tok_e[2 * t + 1] = i1;
        tok_w[2 * t] = p[i0] / sw;  tok_w[2 * t + 1] = p[i1] / sw;
    }
}

// ---------------- atomic-free routing: histogram + prefix + deterministic scatter ----------------
__global__ __launch_bounds__(256) void moe_route(const int* __restrict__ tok_e,
    int* __restrict__ cnt, int* __restrict__ off,
    int* __restrict__ elist, int* __restrict__ tslot)
{
    const int E = blockIdx.x;                 // expert this block owns
    const int tid = threadIdx.x, lane = tid & 63, wave = tid >> 6;
    int ev[32];
#pragma unroll
    for (int i = 0; i < 8; ++i)
        *(i32x4*)&ev[i * 4] = *(const i32x4*)&tok_e[tid * 32 + i * 4];
    int c8[8] = {0,0,0,0,0,0,0,0};
#pragma unroll
    for (int k = 0; k < 32; ++k) ++c8[ev[k] & 7];
    int incl[8];
#pragma unroll
    for (int e = 0; e < 8; ++e) {
        int vv = c8[e];
#pragma unroll
        for (int d = 1; d < 64; d <<= 1) {
            int tmp = __shfl_up(vv, d);
            if (lane >= d) vv += tmp;
        }
        incl[e] = vv;
    }
    __shared__ int wtot[4][8];
    if (lane == 63)
#pragma unroll
        for (int e = 0; e < 8; ++e) wtot[wave][e] = incl[e];
    __syncthreads();
    int tot[8];
#pragma unroll
    for (int e = 0; e < 8; ++e) tot[e] = wtot[0][e] + wtot[1][e] + wtot[2][e] + wtot[3][e];
    int waveoff = 0;
    for (int w = 0; w < 4; ++w) if (w < wave) waveoff += wtot[w][E];
    int offE = 0;
#pragma unroll
    for (int e = 0; e < 8; ++e) if (e < E) offE += tot[e];
    int rank = offE + waveoff + (incl[E] - c8[E]);
#pragma unroll
    for (int k = 0; k < 32; ++k) {
        if ((ev[k] & 7) == E) {
            int p = tid * 32 + k;
            elist[rank] = p >> 1;
            tslot[p] = rank;
            ++rank;
        }
    }
    if (tid == 0) { cnt[E] = tot[E]; off[E] = offE; }
}

// ---------------- RoPE on q + k_r, single launch ----------------
__global__ __launch_bounds__(256) void rope_all(u16* __restrict__ proj)
{
    int idx = blockIdx.x * 256 + threadIdx.x;     // T_*17*32
    int i = idx & 31;
    int r = idx >> 5;
    int t = r / 17, which = r - t * 17;
    int s = t & (S_ - 1);
    float inv = __expf(-(float)i * 0.28782313662425575f);  // ln(10000)/32
    float ang = (float)s * inv;
    float c = cosf(ang), sn = sinf(ang);
    u16* base = proj + (size_t)t * 2688 + (which < 16 ? which * 128 + 64 : 2560);
    float t1 = b2f(base[i]), t2 = b2f(base[32 + i]);
    base[i]      = f2b(t1 * c - t2 * sn);
    base[32 + i] = f2b(t2 * c + t1 * sn);
}

// ---------------- flash attention, BQ=64, transposed-S, T14 + T2 swizzle + balanced qt ----------------
__global__ __launch_bounds__(256, 4) void attn_flash(const u16* __restrict__ proj,
    const u16* __restrict__ kc, const u16* __restrict__ vt, u16* __restrict__ ctx)
{
    const int qidx = blockIdx.x >> 5;
    const int qt = (qidx < 8) ? (31 - qidx) : (qidx < 16) ? (qidx - 8)
                 : (qidx < 24) ? (39 - qidx) : (qidx - 16);
    const int bh = blockIdx.x & 31;
    const int b = bh >> 4, h = bh & 15;
    const int q0 = qt * 64;
    const int tid = threadIdx.x, lane = tid & 63, wave = tid >> 6;
    const int quad = lane >> 4, rr = lane & 15, q8 = quad * 8;
    const int wm2 = wave * 16;

    __shared__ u16 Ks[64 * 128];   // [key][d], XOR-swizzled cols
    __shared__ u16 Ps[64 * 64];    // [qrow][key], XOR-swizzled cols, wave-private rows

    const long tbase = (long)b * S_ + q0;
    short8 qf[4];
#pragma unroll
    for (int d0 = 0; d0 < 4; ++d0)
        qf[d0] = *(const short8*)&proj[(tbase + wm2 + rr) * 2688 + h * 128 + d0 * 32 + q8];

    f32x4 accO[4];                 // O^T: [vi], lane: vd=vi*16+quad*4+rg, qrow=rr
    float m_i = -3e38f, l_i = 0.f;
#pragma unroll
    for (int vi = 0; vi < 4; ++vi)
#pragma unroll
        for (int rg = 0; rg < 4; ++rg) accO[vi][rg] = 0.f;
    const float sc = 0.08838834764831845f * 1.4426950408889634f;

    // staging geometry: thread owns rows srow0, srow0+32, 16B granule sg (logical)
    const int srow0 = tid >> 3, sg = tid & 7;
    const int swz = sg ^ (srow0 & 7);                    // swizzled granule
    const u16* kcp = kc   + ((long)b * S_ + srow0) * 1024 + h * 64 + sg * 8;
    const u16* krp = proj + ((long)b * S_ + srow0) * 2688 + 2560 + sg * 8;
    const u16* vbase = vt + (size_t)(h * 64 + rr) * 4096 + b * 2048 + q8;
    const int rg7 = rr & 7;
    int rdcol[4];
#pragma unroll
    for (int d0 = 0; d0 < 4; ++d0) rdcol[d0] = ((d0 * 4 + quad) ^ rg7) * 8;
    const int prcol0 = (((quad * 16) ^ (rg7 << 4)) >> 1);        // Ps read col, kc0=0
    const int prcol1 = (((64 + quad * 16) ^ (rg7 << 4)) >> 1);   // Ps read col, kc0=32

    const int nkt = qt + 1;
    // prologue: load tile 0 staging into regs
    short8 rk0 = *(const short8*)(kcp);
    short8 rk1 = *(const short8*)(kcp + 32 * 1024);
    short8 rm0 = *(const short8*)(krp);
    short8 rm1 = *(const short8*)(krp + (size_t)32 * 2688);

    for (int kt = 0; kt < nkt; ++kt) {
        const int k0 = kt * 64;
        // write current tile to LDS, swizzled (waits only on this tile's loads)
        *(short8*)&Ks[srow0 * 128 + swz * 8]             = rk0;
        *(short8*)&Ks[(srow0 + 32) * 128 + swz * 8]      = rk1;
        *(short8*)&Ks[srow0 * 128 + 64 + swz * 8]        = rm0;
        *(short8*)&Ks[(srow0 + 32) * 128 + 64 + swz * 8] = rm1;
        __syncthreads();

        // T14: issue next tile's staging loads now; consumed at next iter's write
        const size_t k0s = (kt + 1 < nkt) ? (size_t)(k0 + 64) : 0;   // clamp (safe dummy)
        short8 nk0 = *(const short8*)(kcp + k0s * 1024);
        short8 nk1 = *(const short8*)(kcp + k0s * 1024 + 32 * 1024);
        short8 nm0 = *(const short8*)(krp + k0s * 2688);
        short8 nm1 = *(const short8*)(krp + k0s * 2688 + (size_t)32 * 2688);

        // S^T = K·Q^T (swizzled Ks reads)
        f32x4 accS[4];
#pragma unroll
        for (int ki = 0; ki < 4; ++ki)
#pragma unroll
            for (int rg = 0; rg < 4; ++rg) accS[ki][rg] = 0.f;
        __builtin_amdgcn_s_setprio(1);
#pragma unroll
        for (int d0 = 0; d0 < 4; ++d0) {
            short8 kf[4];
#pragma unroll
            for (int ki = 0; ki < 4; ++ki) kf[ki] = *(const short8*)&Ks[(ki * 16 + rr) * 128 + rdcol[d0]];
#pragma unroll
            for (int ki = 0; ki < 4; ++ki) accS[ki] = MFMA(kf[ki], qf[d0], accS[ki]);
        }
        __builtin_amdgcn_s_setprio(0);
        __syncthreads();   // all waves done reading Ks -> next iter may overwrite

        // V fragments direct from global, issued early to hide under softmax
        short8 vf0[4], vf1[4];
#pragma unroll
        for (int vi = 0; vi < 4; ++vi) {
            vf0[vi] = *(const short8*)(vbase + (size_t)vi * 16 * 4096 + k0);
            vf1[vi] = *(const short8*)(vbase + (size_t)vi * 16 * 4096 + k0 + 32);
        }

        // softmax (masking only on the diagonal tile; block-uniform branch)
        float mx = -3e38f;
        if (kt == qt) {
            const int qg = q0 + wm2 + rr;
#pragma unroll
            for (int ki = 0; ki < 4; ++ki)
#pragma unroll
                for (int rg = 0; rg < 4; ++rg) {
                    float w = accS[ki][rg] * sc;
                    if (k0 + ki * 16 + quad * 4 + rg > qg) w = -1e30f;
                    accS[ki][rg] = w;
                    mx = fmaxf(mx, w);
                }
        } else {
#pragma unroll
            for (int ki = 0; ki < 4; ++ki)
#pragma unroll
                for (int rg = 0; rg < 4; ++rg) {
                    float w = accS[ki][rg] * sc;
                    accS[ki][rg] = w;
                    mx = fmaxf(mx, w);
                }
        }
        mx = fmaxf(mx, __shfl_xor(mx, 16));
        mx = fmaxf(mx, __shfl_xor(mx, 32));
        if (__any(mx > m_i)) {                 // rescale only when some row's max grew (exact)
            float mnew = fmaxf(m_i, mx);
            float alpha = exp2f(m_i - mnew);
            m_i = mnew;
            l_i *= alpha;
#pragma unroll
            for (int vi = 0; vi < 4; ++vi)
#pragma unroll
                for (int rg = 0; rg < 4; ++rg) accO[vi][rg] *= alpha;
        }
        float ps = 0.f;
#pragma unroll
        for (int ki = 0; ki < 4; ++ki) {
            float p0 = exp2f(accS[ki][0] - m_i);
            float p1 = exp2f(accS[ki][1] - m_i);
            float p2 = exp2f(accS[ki][2] - m_i);
            float p3 = exp2f(accS[ki][3] - m_i);
            ps += (p0 + p1) + (p2 + p3);
            u32x2 pk; pk[0] = cvtpk(p0, p1); pk[1] = cvtpk(p2, p3);
            *(u32x2*)&Ps[(wm2 + rr) * 64 + ((((ki * 32 + quad * 8) ^ (rg7 << 4)) >> 1))] = pk;
        }
        ps += __shfl_xor(ps, 16);
        ps += __shfl_xor(ps, 32);
        l_i += ps;

        // O^T += V^T · P^T (Ps rows wave-private: in-wave lgkmcnt ordering only)
        short8 pf0 = *(const short8*)&Ps[(wm2 + rr) * 64 + prcol0];
        short8 pf1 = *(const short8*)&Ps[(wm2 + rr) * 64 + prcol1];
        __builtin_amdgcn_s_setprio(1);
#pragma unroll
        for (int vi = 0; vi < 4; ++vi) accO[vi] = MFMA(vf0[vi], pf0, accO[vi]);
#pragma unroll
        for (int vi = 0; vi < 4; ++vi) accO[vi] = MFMA(vf1[vi], pf1, accO[vi]);
        __builtin_amdgcn_s_setprio(0);

        rk0 = nk0; rk1 = nk1; rm0 = nm0; rm1 = nm1;
    }
    // epilogue: ctx[t][h*64+vd] = O^T/l, packed 8B stores
    {
        float linv = 1.f / l_i;
        long t = tbase + wm2 + rr;
#pragma unroll
        for (int vi = 0; vi < 4; ++vi) {
            u32x2 pk;
            pk[0] = pack2(accO[vi][0] * linv, accO[vi][1] * linv);
            pk[1] = pack2(accO[vi][2] * linv, accO[vi][3] * linv);
            *(u32x2*)&ctx[t * 1024 + h * 64 + vi * 16 + quad * 4] = pk;
        }
    }
}

// ---------------- final (float4 vectorized): out = x_mid + w0*rout[s0] + w1*rout[s1] ----------------
__global__ __launch_bounds__(256) void final_kernel(const float* __restrict__ xm,
    const u16* __restrict__ rout, const int* __restrict__ tok_slot,
    const float* __restrict__ tok_w, float* __restrict__ out)
{
    long i = ((long)blockIdx.x * 256 + threadIdx.x) * 4;
    int t = (int)(i >> 10), d = (int)(i & 1023);
    int s0 = tok_slot[2 * t], s1 = tok_slot[2 * t + 1];
    float w0 = tok_w[2 * t], w1 = tok_w[2 * t + 1];
    f32x4 xv = *(const f32x4*)&xm[i];
    u32x2 r0 = *(const u32x2*)&rout[(long)s0 * 1024 + d];
    u32x2 r1 = *(const u32x2*)&rout[(long)s1 * 1024 + d];
    f32x4 o;
    o[0] = xv[0] + w0 * b2f((u16)(r0[0] & 0xffffu)) + w1 * b2f((u16)(r1[0] & 0xffffu));
    o[1] = xv[1] + w0 * b2f((u16)(r0[0] >> 16))     + w1 * b2f((u16)(r1[0] >> 16));
    o[2] = xv[2] + w0 * b2f((u16)(r0[1] & 0xffffu)) + w1 * b2f((u16)(r1[1] & 0xffffu));
    o[3] = xv[3] + w0 * b2f((u16)(r0[1] >> 16))     + w1 * b2f((u16)(r1[1] >> 16));
    *(f32x4*)&out[i] = o;
}

// ---------------- workspace layout (bytes); peak ~108.2 MB ----------------
#define OFF_XMID   0UL            // f32 4096x1024 (16.78M), lives whole call
#define OFF_H      16777216UL     // h -> h2, bf16 4096x1024 (8.39M)
#define OFF_PROJ   25165824UL     // proj 4096x2688 (22.02M); phase2: wgu_t 10x1Mx2B
#define OFF_WGU    25165824UL
#define OFF_KC     47185920UL     // kc 4096x1024 (8.39M); phase2: wd_t 10x0.5Mx2B
#define OFF_WD     47185920UL
#define OFF_VT     55574528UL     // vt 1024x4096 (8.39M), dead after attn
#define OFF_GUR    57671680UL     // act_r 8192x512 bf16 (8.39M)
#define OFF_CTX    63963136UL     // ctx 4096x1024 (8.39M)
#define OFF_WATT   72351744UL     // wqkv 5.51M, wuk 1.05M, wuv 1.05M, wo 2.10M
#define OFF_ROUT   74448896UL     // rout 8192x1024 bf16 (16.78M), overlays attn weights
#define OFF_GUS    91226112UL     // act_s 4096x1024 bf16 (8.39M)
#define OFF_TOKE   108003328UL
#define OFF_TOKW   108036096UL
#define OFF_TSLOT  108068864UL
#define OFF_ELIST  108101632UL
#define OFF_META   108134400UL

extern "C" void kernel_launch(void* const* d_in, const int* in_sizes, int n_in,
                              void* d_out, int out_size, void* d_ws, size_t ws_size,
                              hipStream_t stream)
{
    const float* x       = (const float*)d_in[0];
    const float* w_q     = (const float*)d_in[2];
    const float* w_dkv   = (const float*)d_in[3];
    const float* w_uk    = (const float*)d_in[4];
    const float* w_uv    = (const float*)d_in[5];
    const float* w_kr    = (const float*)d_in[6];
    const float* w_o     = (const float*)d_in[7];
    const float* attn_nw = (const float*)d_in[8];
    const float* mlp_nw  = (const float*)d_in[9];
    const float* gate_w  = (const float*)d_in[10];
    const float* wr_gate = (const float*)d_in[11];
    const float* wr_up   = (const float*)d_in[12];
    const float* wr_down = (const float*)d_in[13];
    const float* ws_gate = (const float*)d_in[14];
    const float* ws_up   = (const float*)d_in[15];
    const float* ws_down = (const float*)d_in[16];
    float* out = (float*)d_out;

    char* W = (char*)d_ws;
    float* x_mid = (float*)(W + OFF_XMID);
    u16* h      = (u16*)(W + OFF_H);
    u16* h2     = (u16*)(W + OFF_H);
    u16* proj   = (u16*)(W + OFF_PROJ);
    u16* wgu_t  = (u16*)(W + OFF_WGU);
    u16* kc     = (u16*)(W + OFF_KC);
    u16* wd_t   = (u16*)(W + OFF_WD);
    u16* vt     = (u16*)(W + OFF_VT);
    u16* act_r  = (u16*)(W + OFF_GUR);
    u16* ctx    = (u16*)(W + OFF_CTX);
    u16* wqkv_t = (u16*)(W + OFF_WATT);
    u16* wuk_t  = wqkv_t + 2688 * 1024;
    u16* wuv_t  = wuk_t + 1024 * 512;
    u16* wo_t   = wuv_t + 1024 * 512;
    u16* rout   = (u16*)(W + OFF_ROUT);
    u16* act_s  = (u16*)(W + OFF_GUS);
    int*   tok_e = (int*)(W + OFF_TOKE);
    float* tok_w = (float*)(W + OFF_TOKW);
    int*   tslot = (int*)(W + OFF_TSLOT);
    int*   elist = (int*)(W + OFF_ELIST);
    int*   meta  = (int*)(W + OFF_META);
    int* cnt = meta, * off = meta + 8;

    dim3 tb(32, 8);
    // attn weights, 2 merged launches
    transpose_attn_a<<<dim3(82, 32), tb, 0, stream>>>(w_q, w_dkv, w_kr, wqkv_t);
    transpose_attn_b<<<dim3(32, 64), tb, 0, stream>>>(w_uk, w_uv, w_o, wuk_t, wuv_t, wo_t);

    // attention path (RoPE as standalone kernel; fusion into the GEMM regressed r9)
    rmsnorm_wave<<<T_ / 4, 256, 0, stream>>>(x, attn_nw, h);
    gemm_k<<<dim3(21, 32), 256, 0, stream>>>(h, 1024, wqkv_t, 1024, proj, 2688, 1024, 1, nullptr);
    rope_all<<<(T_ * 17 * 32) / 256, 256, 0, stream>>>(proj);
    gemm_dual<<<dim3(32, 32, 2), 256, 0, stream>>>(
        proj + 2048, 2688, wuk_t, 512, kc, 1024, 8, 32,
        wuv_t, 512, proj + 2048, 2688, vt, 4096, 32, 8);
    attn_flash<<<1024, 256, 0, stream>>>(proj, kc, vt, ctx);
    gemm_k<<<dim3(8, 32), 256, 0, stream>>>(ctx, 1024, wo_t, 1024, x_mid, 1024, 1024, 3, x);

    // MoE weights, 2 tight-grid launches (overlays proj/kc after attn)
    transpose_moe_gu<<<dim3(16, 32, 20), tb, 0, stream>>>(wr_gate, wr_up, ws_gate, ws_up, wgu_t);
    transpose_moe_down<<<dim3(32, 16, 10), tb, 0, stream>>>(wr_down, ws_down, wd_t);

    // MoE path: fused rmsnorm+gate -> atomic-free routing
    rmsnorm_gate_fused<<<T_ / 4, 256, 0, stream>>>(x_mid, mlp_nw, gate_w, h2, tok_e, tok_w);
    moe_route<<<8, 256, 0, stream>>>(tok_e, cnt, off, elist, tslot);
    // gate|up (+fused silu) for routed + shared in ONE launch; down in ONE launch
    gemm_guall<<<dim3(8, 32, 10), 256, 0, stream>>>(h2, wgu_t, act_r, act_s, cnt, off, elist);
    gemm_downall<<<dim3(8, 32, 9), 256, 0, stream>>>(act_r, act_s, wd_t, rout, x_mid, cnt, off);
    final_kernel<<<(T_ * D_) / 1024, 256, 0, stream>>>(x_mid, rout, tslot, tok_w, out);
}